// Round 1
// baseline (1684.677 us; speedup 1.0000x reference)
//
#include <hip/hip_runtime.h>
#include <hip/hip_bf16.h>
#include <math.h>

#define D_MODEL 1024
#define D_STATE 16
#define D_CONV 4
#define D_INNER 2048
#define DT_RANK 64
#define BATCH 2
#define SEQ 2048
#define NTOK (BATCH*SEQ)   // 4096
#define EPS 1e-5f

// ---------------- RMSNorm: one block per token ----------------
__global__ __launch_bounds__(256) void rmsnorm_kernel(const float* __restrict__ x,
                                                      const float* __restrict__ w,
                                                      float* __restrict__ xn) {
  int tok = blockIdx.x;
  const float* xr = x + (size_t)tok * D_MODEL;
  float* xo = xn + (size_t)tok * D_MODEL;
  int t = threadIdx.x;
  float4 v = ((const float4*)xr)[t];
  float ss = v.x*v.x + v.y*v.y + v.z*v.z + v.w*v.w;
  #pragma unroll
  for (int off = 32; off > 0; off >>= 1) ss += __shfl_down(ss, off, 64);
  __shared__ float wsum[4];
  __shared__ float rinv_s;
  int lane = t & 63, wv = t >> 6;
  if (lane == 0) wsum[wv] = ss;
  __syncthreads();
  if (t == 0) {
    float tot = wsum[0] + wsum[1] + wsum[2] + wsum[3];
    rinv_s = 1.0f / sqrtf(tot / (float)D_MODEL + EPS);
  }
  __syncthreads();
  float rinv = rinv_s;
  float4 g = ((const float4*)w)[t];
  float4 o;
  o.x = v.x * rinv * g.x;
  o.y = v.y * rinv * g.y;
  o.z = v.z * rinv * g.z;
  o.w = v.w * rinv * g.w;
  ((float4*)xo)[t] = o;
}

// ---------------- Generic fp32 GEMM: C[m,n] = sum_k A[m*lda+k] * W[n*K+k] ----------------
// EPI: 0 = none, 1 = softplus(acc + bias[n]), 2 = acc + resid[m*ldc+n]
#define BM 64
#define BN 64
#define BKK 16

template<int EPI>
__global__ __launch_bounds__(256) void gemm_kernel(
    const float* __restrict__ A, int lda,
    const float* __restrict__ W,
    float* __restrict__ C, int ldc,
    int M, int N, int K,
    const float* __restrict__ bias,
    const float* __restrict__ resid)
{
  __shared__ float As[BKK][BM + 16];   // padded: row stride 320B (16B aligned, conflict-light)
  __shared__ float Ws[BKK][BN + 16];
  int tid = threadIdx.x;
  int bm = blockIdx.x * BM;
  int bn = blockIdx.y * BN;
  int lr = tid >> 2;            // 0..63 tile row for staging
  int lc = (tid & 3) << 2;      // 0/4/8/12 k-col for staging (float4)
  int tr = (tid >> 4) << 2;     // micro-tile row base
  int tc = (tid & 15) << 2;     // micro-tile col base
  float acc[4][4] = {};
  const float* Aptr = A + (size_t)(bm + lr) * lda + lc;
  int wr = bn + lr;
  bool wok = wr < N;
  const float* Wptr = W + (size_t)wr * K + lc;

  for (int k0 = 0; k0 < K; k0 += BKK) {
    float4 av = *(const float4*)(Aptr + k0);
    float4 wv2 = wok ? *(const float4*)(Wptr + k0) : make_float4(0.f,0.f,0.f,0.f);
    __syncthreads();
    As[lc+0][lr] = av.x; As[lc+1][lr] = av.y; As[lc+2][lr] = av.z; As[lc+3][lr] = av.w;
    Ws[lc+0][lr] = wv2.x; Ws[lc+1][lr] = wv2.y; Ws[lc+2][lr] = wv2.z; Ws[lc+3][lr] = wv2.w;
    __syncthreads();
    #pragma unroll
    for (int kk = 0; kk < BKK; ++kk) {
      float a0 = As[kk][tr+0], a1 = As[kk][tr+1], a2 = As[kk][tr+2], a3 = As[kk][tr+3];
      float w0 = Ws[kk][tc+0], w1 = Ws[kk][tc+1], w2 = Ws[kk][tc+2], w3 = Ws[kk][tc+3];
      acc[0][0] = fmaf(a0,w0,acc[0][0]); acc[0][1] = fmaf(a0,w1,acc[0][1]);
      acc[0][2] = fmaf(a0,w2,acc[0][2]); acc[0][3] = fmaf(a0,w3,acc[0][3]);
      acc[1][0] = fmaf(a1,w0,acc[1][0]); acc[1][1] = fmaf(a1,w1,acc[1][1]);
      acc[1][2] = fmaf(a1,w2,acc[1][2]); acc[1][3] = fmaf(a1,w3,acc[1][3]);
      acc[2][0] = fmaf(a2,w0,acc[2][0]); acc[2][1] = fmaf(a2,w1,acc[2][1]);
      acc[2][2] = fmaf(a2,w2,acc[2][2]); acc[2][3] = fmaf(a2,w3,acc[2][3]);
      acc[3][0] = fmaf(a3,w0,acc[3][0]); acc[3][1] = fmaf(a3,w1,acc[3][1]);
      acc[3][2] = fmaf(a3,w2,acc[3][2]); acc[3][3] = fmaf(a3,w3,acc[3][3]);
    }
  }

  #pragma unroll
  for (int i = 0; i < 4; ++i) {
    int m = bm + tr + i;
    #pragma unroll
    for (int j = 0; j < 4; ++j) {
      int nn = bn + tc + j;
      if (nn >= N) continue;
      float v = acc[i][j];
      if (EPI == 1) {
        float s = v + bias[nn];
        v = fmaxf(s, 0.f) + log1pf(__expf(-fabsf(s)));   // stable softplus
      } else if (EPI == 2) {
        v += resid[(size_t)m * ldc + nn];
      }
      C[(size_t)m * ldc + nn] = v;
    }
  }
}

// ---------------- depthwise causal conv1d (k=4) + SiLU ----------------
__global__ __launch_bounds__(256) void conv_silu_kernel(
    const float* __restrict__ xz, const float* __restrict__ cw,
    const float* __restrict__ cb, float* __restrict__ xc)
{
  int idx = blockIdx.x * 256 + threadIdx.x;   // over NTOK*D_INNER
  int d = idx & (D_INNER - 1);
  int tok = idx >> 11;
  int l = tok & (SEQ - 1);
  float w0 = cw[d*4+0], w1 = cw[d*4+1], w2 = cw[d*4+2], w3 = cw[d*4+3];
  const float* xi = xz + (size_t)tok * (2*D_INNER) + d;
  float s = cb[d];
  s += (l >= 3 ? xi[-3*(2*D_INNER)] : 0.f) * w0;
  s += (l >= 2 ? xi[-2*(2*D_INNER)] : 0.f) * w1;
  s += (l >= 1 ? xi[-1*(2*D_INNER)] : 0.f) * w2;
  s += xi[0] * w3;
  xc[idx] = s / (1.f + __expf(-s));          // SiLU
}

// ---------------- selective scan ----------------
// block = 256 threads = 16 d-channels x 16 states; grid = B * (D_INNER/16)
__global__ __launch_bounds__(256) void scan_kernel(
    const float* __restrict__ delta, const float* __restrict__ dbl,
    const float* __restrict__ xc, const float* __restrict__ xz,
    const float* __restrict__ A_log, const float* __restrict__ Dp,
    float* __restrict__ y)
{
  int b = blockIdx.x >> 7;        // 128 d-blocks per batch
  int dblk = blockIdx.x & 127;
  int t = threadIdx.x;
  int dl = t >> 4, n = t & 15;
  int d = dblk * 16 + dl;
  float Adn = -__expf(A_log[d * D_STATE + n]);
  float Dpd = Dp[d];
  float h = 0.f;
  const int tok0 = b * SEQ;

  float dlA[4], bvA[4], cvA[4], xcA[4], zvA[4];
  float dlB[4], bvB[4], cvB[4], xcB[4], zvB[4];

  auto loadc = [&](float (&dl_)[4], float (&bv_)[4], float (&cv_)[4],
                   float (&xc_)[4], float (&zv_)[4], int l0) {
    #pragma unroll
    for (int j = 0; j < 4; ++j) {
      int ll = l0 + j; if (ll > SEQ - 1) ll = SEQ - 1;   // clamp (values unused)
      size_t tok = (size_t)(tok0 + ll);
      dl_[j] = delta[tok * D_INNER + d];
      xc_[j] = xc[tok * D_INNER + d];
      bv_[j] = dbl[tok * 96 + 64 + n];
      cv_[j] = dbl[tok * 96 + 80 + n];
      zv_[j] = (n == 0) ? xz[tok * (2*D_INNER) + D_INNER + d] : 0.f;
    }
  };
  auto comp = [&](float (&dl_)[4], float (&bv_)[4], float (&cv_)[4],
                  float (&xc_)[4], float (&zv_)[4], int l0) {
    #pragma unroll
    for (int j = 0; j < 4; ++j) {
      float dA = __expf(dl_[j] * Adn);
      float dBu = dl_[j] * bv_[j] * xc_[j];
      h = fmaf(dA, h, dBu);
      float p = h * cv_[j];
      p += __shfl_xor(p, 1, 64);
      p += __shfl_xor(p, 2, 64);
      p += __shfl_xor(p, 4, 64);
      p += __shfl_xor(p, 8, 64);
      if (n == 0) {
        float yy = p + xc_[j] * Dpd;
        float z = zv_[j];
        float sz = z / (1.f + __expf(-z));
        y[(size_t)(tok0 + l0 + j) * D_INNER + d] = yy * sz;
      }
    }
  };

  loadc(dlA, bvA, cvA, xcA, zvA, 0);
  for (int l0 = 0; l0 < SEQ; l0 += 8) {
    loadc(dlB, bvB, cvB, xcB, zvB, l0 + 4);
    comp (dlA, bvA, cvA, xcA, zvA, l0);
    loadc(dlA, bvA, cvA, xcA, zvA, l0 + 8);
    comp (dlB, bvB, cvB, xcB, zvB, l0 + 4);
  }
}

// ---------------- launch ----------------
extern "C" void kernel_launch(void* const* d_in, const int* in_sizes, int n_in,
                              void* d_out, int out_size, void* d_ws, size_t ws_size,
                              hipStream_t stream) {
  const float* x         = (const float*)d_in[0];
  const float* norm_w    = (const float*)d_in[1];
  const float* in_proj_w = (const float*)d_in[2];
  const float* conv_w    = (const float*)d_in[3];
  const float* conv_b    = (const float*)d_in[4];
  const float* x_proj_w  = (const float*)d_in[5];
  const float* dt_proj_w = (const float*)d_in[6];
  const float* dt_proj_b = (const float*)d_in[7];
  const float* A_log     = (const float*)d_in[8];
  const float* Dp        = (const float*)d_in[9];
  const float* out_proj_w= (const float*)d_in[10];
  float* out = (float*)d_out;

  char* ws = (char*)d_ws;
  float* xn    = (float*)(ws);                    // 16 MB
  float* xz    = (float*)(ws + (16ull<<20));      // 64 MB  [tok][4096]: xi | z
  float* xc    = (float*)(ws + (80ull<<20));      // 32 MB
  float* dbl   = (float*)(ws + (112ull<<20));     // 1.5 MB (reserve 2)  [tok][96]: dt|B|C
  float* delta = (float*)(ws + (114ull<<20));     // 32 MB
  float* yb    = (float*)(ws + (146ull<<20));     // 32 MB  (total 178 MB)

  // 1. RMSNorm
  rmsnorm_kernel<<<NTOK, 256, 0, stream>>>(x, norm_w, xn);

  // 2. in_proj: [4096,1024] x [4096,1024]^T -> [4096,4096]
  {
    dim3 g(NTOK/BM, (2*D_INNER)/BN);
    gemm_kernel<0><<<g, 256, 0, stream>>>(xn, D_MODEL, in_proj_w, xz, 2*D_INNER,
                                          NTOK, 2*D_INNER, D_MODEL, nullptr, nullptr);
  }

  // 3. depthwise conv + SiLU
  conv_silu_kernel<<<(NTOK*D_INNER)/256, 256, 0, stream>>>(xz, conv_w, conv_b, xc);

  // 4. x_proj: [4096,2048] x [96,2048]^T -> [4096,96]
  {
    dim3 g(NTOK/BM, (96 + BN - 1)/BN);
    gemm_kernel<0><<<g, 256, 0, stream>>>(xc, D_INNER, x_proj_w, dbl, 96,
                                          NTOK, 96, D_INNER, nullptr, nullptr);
  }

  // 5. dt_proj + softplus: [4096,64(stride 96)] x [2048,64]^T -> [4096,2048]
  {
    dim3 g(NTOK/BM, D_INNER/BN);
    gemm_kernel<1><<<g, 256, 0, stream>>>(dbl, 96, dt_proj_w, delta, D_INNER,
                                          NTOK, D_INNER, DT_RANK, dt_proj_b, nullptr);
  }

  // 6. selective scan (+ skip D, + silu(z) gate)
  scan_kernel<<<BATCH*(D_INNER/16), 256, 0, stream>>>(delta, dbl, xc, xz, A_log, Dp, yb);

  // 7. out_proj + residual: [4096,2048] x [1024,2048]^T + x -> out
  {
    dim3 g(NTOK/BM, D_MODEL/BN);
    gemm_kernel<2><<<g, 256, 0, stream>>>(yb, D_INNER, out_proj_w, out, D_MODEL,
                                          NTOK, D_MODEL, D_INNER, nullptr, x);
  }
}

// Round 3
// 987.459 us; speedup vs baseline: 1.7061x; 1.7061x over previous
//
#include <hip/hip_runtime.h>
#include <hip/hip_bf16.h>
#include <math.h>

#define D_MODEL 1024
#define D_STATE 16
#define D_CONV 4
#define D_INNER 2048
#define DT_RANK 64
#define BATCH 2
#define SEQ 2048
#define NTOK (BATCH*SEQ)   // 4096
#define EPS 1e-5f

typedef __attribute__((ext_vector_type(8))) short short8;
typedef __attribute__((ext_vector_type(4))) float f32x4;
typedef __attribute__((ext_vector_type(4))) unsigned short us4;

__device__ inline unsigned short f2bf(float f) {
  union { __hip_bfloat16 h; unsigned short u; } c;
  c.h = __float2bfloat16(f);
  return c.u;
}

// ---------------- fp32 -> bf16 bulk convert (n multiple of 4) ----------------
__global__ __launch_bounds__(256) void f2bf_kernel(const float* __restrict__ in,
                                                   unsigned short* __restrict__ out, int n) {
  int i = (blockIdx.x * 256 + threadIdx.x) * 4;
  if (i >= n) return;
  float4 v = *(const float4*)(in + i);
  us4 o;
  o[0] = f2bf(v.x); o[1] = f2bf(v.y); o[2] = f2bf(v.z); o[3] = f2bf(v.w);
  *(us4*)(out + i) = o;
}

// ---------------- RMSNorm: one block per token, bf16 output ----------------
__global__ __launch_bounds__(256) void rmsnorm_kernel(const float* __restrict__ x,
                                                      const float* __restrict__ w,
                                                      unsigned short* __restrict__ xn) {
  int tok = blockIdx.x;
  const float* xr = x + (size_t)tok * D_MODEL;
  unsigned short* xo = xn + (size_t)tok * D_MODEL;
  int t = threadIdx.x;
  float4 v = ((const float4*)xr)[t];
  float ss = v.x*v.x + v.y*v.y + v.z*v.z + v.w*v.w;
  #pragma unroll
  for (int off = 32; off > 0; off >>= 1) ss += __shfl_down(ss, off, 64);
  __shared__ float wsum[4];
  __shared__ float rinv_s;
  int lane = t & 63, wv = t >> 6;
  if (lane == 0) wsum[wv] = ss;
  __syncthreads();
  if (t == 0) {
    float tot = wsum[0] + wsum[1] + wsum[2] + wsum[3];
    rinv_s = 1.0f / sqrtf(tot / (float)D_MODEL + EPS);
  }
  __syncthreads();
  float rinv = rinv_s;
  float4 g = ((const float4*)w)[t];
  us4 o;
  o[0] = f2bf(v.x * rinv * g.x);
  o[1] = f2bf(v.y * rinv * g.y);
  o[2] = f2bf(v.z * rinv * g.z);
  o[3] = f2bf(v.w * rinv * g.w);
  *(us4*)(xo + t*4) = o;
}

// ---------------- bf16 MFMA GEMM: C[m,n] = sum_k A[m][k]*W[n][k] ----------------
// 128x128 tile, 4 waves (2x2), each wave 64x64 = 4x4 fragments of 16x16x32.
// LDS is fragment-contiguous: global_load_lds writes base+lane*16B linearly, and we
// pre-swizzle the per-lane GLOBAL source so lane l's 16B IS its MFMA fragment slice.
// A-frag (16x32): lane l -> row=l&15, k=(l>>4)*8..+7 ; B-frag same with col=l&15.
// C/D: col=lane&15, row=(lane>>4)*4+reg  [m89-verified].
// EPI: 0 = none, 2 = + resid[m*ldc+n]
template<int EPI>
__global__ __launch_bounds__(256) void gemm_bf16_kernel(
    const unsigned short* __restrict__ A,   // [M][K] bf16
    const unsigned short* __restrict__ W,   // [N][K] bf16
    float* __restrict__ C, int ldc, int K,
    const float* __restrict__ resid)
{
  __shared__ __align__(16) unsigned short Abuf[8*64*8];  // 8 row-blocks x 64 lanes x 8 bf16 = 8KB
  __shared__ __align__(16) unsigned short Bbuf[8*64*8];
  int tid = threadIdx.x;
  int lane = tid & 63;
  int w = tid >> 6;
  int bm = blockIdx.x * 128;
  int bn = blockIdx.y * 128;
  int wrow = (w >> 1) * 64;   // wave's 64x64 sub-tile origin
  int wcol = (w & 1) * 64;

  int r15 = lane & 15, g = lane >> 4;
  // wave w stages A row-blocks {2w,2w+1} and W col-blocks {2w,2w+1}
  const unsigned short* Ag0 = A + (size_t)(bm + 2*w*16 + r15) * K + g*8;
  const unsigned short* Ag1 = Ag0 + (size_t)16 * K;
  const unsigned short* Wg0 = W + (size_t)(bn + 2*w*16 + r15) * K + g*8;
  const unsigned short* Wg1 = Wg0 + (size_t)16 * K;
  unsigned short* Al0 = &Abuf[(2*w  )*512];   // wave-uniform LDS base; HW adds lane*16B
  unsigned short* Al1 = &Abuf[(2*w+1)*512];
  unsigned short* Bl0 = &Bbuf[(2*w  )*512];
  unsigned short* Bl1 = &Bbuf[(2*w+1)*512];

  f32x4 acc[4][4] = {};

  for (int k0 = 0; k0 < K; k0 += 32) {
    __syncthreads();   // prior iteration's reads complete before overwrite
    __builtin_amdgcn_global_load_lds((const __attribute__((address_space(1))) void*)(Ag0 + k0),
                                     (__attribute__((address_space(3))) void*)Al0, 16, 0, 0);
    __builtin_amdgcn_global_load_lds((const __attribute__((address_space(1))) void*)(Ag1 + k0),
                                     (__attribute__((address_space(3))) void*)Al1, 16, 0, 0);
    __builtin_amdgcn_global_load_lds((const __attribute__((address_space(1))) void*)(Wg0 + k0),
                                     (__attribute__((address_space(3))) void*)Bl0, 16, 0, 0);
    __builtin_amdgcn_global_load_lds((const __attribute__((address_space(1))) void*)(Wg1 + k0),
                                     (__attribute__((address_space(3))) void*)Bl1, 16, 0, 0);
    __syncthreads();   // compiler drains vmcnt(0) before barrier -> staged data visible

    short8 af[4], bfr[4];
    #pragma unroll
    for (int i = 0; i < 4; ++i)
      af[i] = *(const short8*)&Abuf[((wrow >> 4) + i)*512 + lane*8];   // linear: conflict-free
    #pragma unroll
    for (int j = 0; j < 4; ++j)
      bfr[j] = *(const short8*)&Bbuf[((wcol >> 4) + j)*512 + lane*8];
    #pragma unroll
    for (int i = 0; i < 4; ++i)
      #pragma unroll
      for (int j = 0; j < 4; ++j)
        acc[i][j] = __builtin_amdgcn_mfma_f32_16x16x32_bf16(af[i], bfr[j], acc[i][j], 0, 0, 0);
  }

  #pragma unroll
  for (int i = 0; i < 4; ++i) {
    #pragma unroll
    for (int j = 0; j < 4; ++j) {
      #pragma unroll
      for (int r = 0; r < 4; ++r) {
        int row = bm + wrow + i*16 + (lane >> 4)*4 + r;
        int col = bn + wcol + j*16 + (lane & 15);
        float v = acc[i][j][r];
        if (EPI == 2) v += resid[(size_t)row * ldc + col];
        C[(size_t)row * ldc + col] = v;
      }
    }
  }
}

// ---------------- Generic fp32 GEMM (small ops): C[m,n] = sum_k A[m*lda+k]*W[n*K+k] ----
// EPI: 0 = none, 1 = softplus(acc + bias[n])
#define BM 64
#define BN 64
#define BKK 16

template<int EPI>
__global__ __launch_bounds__(256) void gemm_kernel(
    const float* __restrict__ A, int lda,
    const float* __restrict__ W,
    float* __restrict__ C, int ldc,
    int M, int N, int K,
    const float* __restrict__ bias)
{
  __shared__ float As[BKK][BM + 16];
  __shared__ float Ws[BKK][BN + 16];
  int tid = threadIdx.x;
  int bm = blockIdx.x * BM;
  int bn = blockIdx.y * BN;
  int lr = tid >> 2;
  int lc = (tid & 3) << 2;
  int tr = (tid >> 4) << 2;
  int tc = (tid & 15) << 2;
  float acc[4][4] = {};
  const float* Aptr = A + (size_t)(bm + lr) * lda + lc;
  int wr = bn + lr;
  bool wok = wr < N;
  const float* Wptr = W + (size_t)wr * K + lc;

  for (int k0 = 0; k0 < K; k0 += BKK) {
    float4 av = *(const float4*)(Aptr + k0);
    float4 wv2 = wok ? *(const float4*)(Wptr + k0) : make_float4(0.f,0.f,0.f,0.f);
    __syncthreads();
    As[lc+0][lr] = av.x; As[lc+1][lr] = av.y; As[lc+2][lr] = av.z; As[lc+3][lr] = av.w;
    Ws[lc+0][lr] = wv2.x; Ws[lc+1][lr] = wv2.y; Ws[lc+2][lr] = wv2.z; Ws[lc+3][lr] = wv2.w;
    __syncthreads();
    #pragma unroll
    for (int kk = 0; kk < BKK; ++kk) {
      float a0 = As[kk][tr+0], a1 = As[kk][tr+1], a2 = As[kk][tr+2], a3 = As[kk][tr+3];
      float w0 = Ws[kk][tc+0], w1 = Ws[kk][tc+1], w2 = Ws[kk][tc+2], w3 = Ws[kk][tc+3];
      acc[0][0] = fmaf(a0,w0,acc[0][0]); acc[0][1] = fmaf(a0,w1,acc[0][1]);
      acc[0][2] = fmaf(a0,w2,acc[0][2]); acc[0][3] = fmaf(a0,w3,acc[0][3]);
      acc[1][0] = fmaf(a1,w0,acc[1][0]); acc[1][1] = fmaf(a1,w1,acc[1][1]);
      acc[1][2] = fmaf(a1,w2,acc[1][2]); acc[1][3] = fmaf(a1,w3,acc[1][3]);
      acc[2][0] = fmaf(a2,w0,acc[2][0]); acc[2][1] = fmaf(a2,w1,acc[2][1]);
      acc[2][2] = fmaf(a2,w2,acc[2][2]); acc[2][3] = fmaf(a2,w3,acc[2][3]);
      acc[3][0] = fmaf(a3,w0,acc[3][0]); acc[3][1] = fmaf(a3,w1,acc[3][1]);
      acc[3][2] = fmaf(a3,w2,acc[3][2]); acc[3][3] = fmaf(a3,w3,acc[3][3]);
    }
  }

  #pragma unroll
  for (int i = 0; i < 4; ++i) {
    int m = bm + tr + i;
    #pragma unroll
    for (int j = 0; j < 4; ++j) {
      int nn = bn + tc + j;
      if (nn >= N) continue;
      float v = acc[i][j];
      if (EPI == 1) {
        float s = v + bias[nn];
        v = fmaxf(s, 0.f) + log1pf(__expf(-fabsf(s)));
      }
      C[(size_t)m * ldc + nn] = v;
    }
  }
}

// ---------------- depthwise causal conv1d (k=4) + SiLU ----------------
__global__ __launch_bounds__(256) void conv_silu_kernel(
    const float* __restrict__ xz, const float* __restrict__ cw,
    const float* __restrict__ cb, float* __restrict__ xc)
{
  int idx = blockIdx.x * 256 + threadIdx.x;
  int d = idx & (D_INNER - 1);
  int tok = idx >> 11;
  int l = tok & (SEQ - 1);
  float w0 = cw[d*4+0], w1 = cw[d*4+1], w2 = cw[d*4+2], w3 = cw[d*4+3];
  const float* xi = xz + (size_t)tok * (2*D_INNER) + d;
  float s = cb[d];
  s += (l >= 3 ? xi[-3*(2*D_INNER)] : 0.f) * w0;
  s += (l >= 2 ? xi[-2*(2*D_INNER)] : 0.f) * w1;
  s += (l >= 1 ? xi[-1*(2*D_INNER)] : 0.f) * w2;
  s += xi[0] * w3;
  xc[idx] = s / (1.f + __expf(-s));
}

// ---------------- selective scan (bf16 output) ----------------
__global__ __launch_bounds__(256) void scan_kernel(
    const float* __restrict__ delta, const float* __restrict__ dbl,
    const float* __restrict__ xc, const float* __restrict__ xz,
    const float* __restrict__ A_log, const float* __restrict__ Dp,
    unsigned short* __restrict__ y)
{
  int b = blockIdx.x >> 7;
  int dblk = blockIdx.x & 127;
  int t = threadIdx.x;
  int dl = t >> 4, n = t & 15;
  int d = dblk * 16 + dl;
  float Adn = -__expf(A_log[d * D_STATE + n]);
  float Dpd = Dp[d];
  float h = 0.f;
  const int tok0 = b * SEQ;

  float dlA[4], bvA[4], cvA[4], xcA[4], zvA[4];
  float dlB[4], bvB[4], cvB[4], xcB[4], zvB[4];

  auto loadc = [&](float (&dl_)[4], float (&bv_)[4], float (&cv_)[4],
                   float (&xc_)[4], float (&zv_)[4], int l0) {
    #pragma unroll
    for (int j = 0; j < 4; ++j) {
      int ll = l0 + j; if (ll > SEQ - 1) ll = SEQ - 1;
      size_t tok = (size_t)(tok0 + ll);
      dl_[j] = delta[tok * D_INNER + d];
      xc_[j] = xc[tok * D_INNER + d];
      bv_[j] = dbl[tok * 96 + 64 + n];
      cv_[j] = dbl[tok * 96 + 80 + n];
      zv_[j] = (n == 0) ? xz[tok * (2*D_INNER) + D_INNER + d] : 0.f;
    }
  };
  auto comp = [&](float (&dl_)[4], float (&bv_)[4], float (&cv_)[4],
                  float (&xc_)[4], float (&zv_)[4], int l0) {
    #pragma unroll
    for (int j = 0; j < 4; ++j) {
      float dA = __expf(dl_[j] * Adn);
      float dBu = dl_[j] * bv_[j] * xc_[j];
      h = fmaf(dA, h, dBu);
      float p = h * cv_[j];
      p += __shfl_xor(p, 1, 64);
      p += __shfl_xor(p, 2, 64);
      p += __shfl_xor(p, 4, 64);
      p += __shfl_xor(p, 8, 64);
      if (n == 0) {
        float yy = p + xc_[j] * Dpd;
        float z = zv_[j];
        float sz = z / (1.f + __expf(-z));
        y[(size_t)(tok0 + l0 + j) * D_INNER + d] = f2bf(yy * sz);
      }
    }
  };

  loadc(dlA, bvA, cvA, xcA, zvA, 0);
  for (int l0 = 0; l0 < SEQ; l0 += 8) {
    loadc(dlB, bvB, cvB, xcB, zvB, l0 + 4);
    comp (dlA, bvA, cvA, xcA, zvA, l0);
    loadc(dlA, bvA, cvA, xcA, zvA, l0 + 8);
    comp (dlB, bvB, cvB, xcB, zvB, l0 + 4);
  }
}

// ---------------- launch ----------------
extern "C" void kernel_launch(void* const* d_in, const int* in_sizes, int n_in,
                              void* d_out, int out_size, void* d_ws, size_t ws_size,
                              hipStream_t stream) {
  const float* x         = (const float*)d_in[0];
  const float* norm_w    = (const float*)d_in[1];
  const float* in_proj_w = (const float*)d_in[2];
  const float* conv_w    = (const float*)d_in[3];
  const float* conv_b    = (const float*)d_in[4];
  const float* x_proj_w  = (const float*)d_in[5];
  const float* dt_proj_w = (const float*)d_in[6];
  const float* dt_proj_b = (const float*)d_in[7];
  const float* A_log     = (const float*)d_in[8];
  const float* Dp        = (const float*)d_in[9];
  const float* out_proj_w= (const float*)d_in[10];
  float* out = (float*)d_out;

  char* ws = (char*)d_ws;
  float*          xz     = (float*)(ws);                    //  0..64 MB  [tok][4096]: xi | z
  float*          xc     = (float*)(ws + ( 64ull<<20));     // 64..96 MB
  float*          dbl    = (float*)(ws + ( 96ull<<20));     // 96..98 MB  [tok][96]: dt|B|C
  float*          delta  = (float*)(ws + ( 98ull<<20));     // 98..130 MB
  unsigned short* xn_bf  = (unsigned short*)(ws + (130ull<<20));  // 130..138 MB
  unsigned short* w_in_bf  = (unsigned short*)(ws + (138ull<<20));// 138..146 MB
  unsigned short* w_out_bf = (unsigned short*)(ws + (146ull<<20));// 146..150 MB
  unsigned short* yb_bf  = (unsigned short*)(ws + (150ull<<20));  // 150..166 MB

  // 1. RMSNorm -> bf16
  rmsnorm_kernel<<<NTOK, 256, 0, stream>>>(x, norm_w, xn_bf);

  // 1b. weight conversions fp32 -> bf16
  f2bf_kernel<<<(2*D_INNER*D_MODEL)/1024, 256, 0, stream>>>(in_proj_w, w_in_bf, 2*D_INNER*D_MODEL);
  f2bf_kernel<<<(D_MODEL*D_INNER)/1024, 256, 0, stream>>>(out_proj_w, w_out_bf, D_MODEL*D_INNER);

  // 2. in_proj (bf16 MFMA): [4096,1024] x [4096,1024]^T -> [4096,4096] fp32
  {
    dim3 g(NTOK/128, (2*D_INNER)/128);
    gemm_bf16_kernel<0><<<g, 256, 0, stream>>>(xn_bf, w_in_bf, xz, 2*D_INNER, D_MODEL, nullptr);
  }

  // 3. depthwise conv + SiLU
  conv_silu_kernel<<<(NTOK*D_INNER)/256, 256, 0, stream>>>(xz, conv_w, conv_b, xc);

  // 4. x_proj (fp32): [4096,2048] x [96,2048]^T -> [4096,96]
  {
    dim3 g(NTOK/BM, (96 + BN - 1)/BN);
    gemm_kernel<0><<<g, 256, 0, stream>>>(xc, D_INNER, x_proj_w, dbl, 96,
                                          NTOK, 96, D_INNER, nullptr);
  }

  // 5. dt_proj + softplus (fp32): [4096,64(stride 96)] x [2048,64]^T -> [4096,2048]
  {
    dim3 g(NTOK/BM, D_INNER/BN);
    gemm_kernel<1><<<g, 256, 0, stream>>>(dbl, 96, dt_proj_w, delta, D_INNER,
                                          NTOK, D_INNER, DT_RANK, dt_proj_b);
  }

  // 6. selective scan -> bf16 y
  scan_kernel<<<BATCH*(D_INNER/16), 256, 0, stream>>>(delta, dbl, xc, xz, A_log, Dp, yb_bf);

  // 7. out_proj (bf16 MFMA) + residual: [4096,2048] x [1024,2048]^T + x -> out
  {
    dim3 g(NTOK/128, D_MODEL/128);
    gemm_bf16_kernel<2><<<g, 256, 0, stream>>>(yb_bf, w_out_bf, out, D_MODEL, D_INNER, x);
  }
}

// Round 5
// 515.573 us; speedup vs baseline: 3.2676x; 1.9153x over previous
//
#include <hip/hip_runtime.h>
#include <hip/hip_bf16.h>
#include <math.h>

#define D_MODEL 1024
#define D_STATE 16
#define D_CONV 4
#define D_INNER 2048
#define DT_RANK 64
#define BATCH 2
#define SEQ 2048
#define NTOK (BATCH*SEQ)   // 4096
#define EPS 1e-5f
#define CCH 32             // scan chunks per sequence
#define TCH (SEQ/CCH)      // 64 tokens per chunk

typedef __attribute__((ext_vector_type(8))) short short8;
typedef __attribute__((ext_vector_type(4))) float f32x4;
typedef __attribute__((ext_vector_type(4))) unsigned short us4;

__device__ inline unsigned short f2bf(float f) {
  union { __hip_bfloat16 h; unsigned short u; } c;
  c.h = __float2bfloat16(f);
  return c.u;
}

// ---------------- fp32 -> bf16 bulk convert (n multiple of 4) ----------------
__global__ __launch_bounds__(256) void f2bf_kernel(const float* __restrict__ in,
                                                   unsigned short* __restrict__ out, int n) {
  int i = (blockIdx.x * 256 + threadIdx.x) * 4;
  if (i >= n) return;
  float4 v = *(const float4*)(in + i);
  us4 o;
  o[0] = f2bf(v.x); o[1] = f2bf(v.y); o[2] = f2bf(v.z); o[3] = f2bf(v.w);
  *(us4*)(out + i) = o;
}

// ---------------- RMSNorm: one block per token, bf16 output ----------------
__global__ __launch_bounds__(256) void rmsnorm_kernel(const float* __restrict__ x,
                                                      const float* __restrict__ w,
                                                      unsigned short* __restrict__ xn) {
  int tok = blockIdx.x;
  const float* xr = x + (size_t)tok * D_MODEL;
  unsigned short* xo = xn + (size_t)tok * D_MODEL;
  int t = threadIdx.x;
  float4 v = ((const float4*)xr)[t];
  float ss = v.x*v.x + v.y*v.y + v.z*v.z + v.w*v.w;
  #pragma unroll
  for (int off = 32; off > 0; off >>= 1) ss += __shfl_down(ss, off, 64);
  __shared__ float wsum[4];
  __shared__ float rinv_s;
  int lane = t & 63, wv = t >> 6;
  if (lane == 0) wsum[wv] = ss;
  __syncthreads();
  if (t == 0) {
    float tot = wsum[0] + wsum[1] + wsum[2] + wsum[3];
    rinv_s = 1.0f / sqrtf(tot / (float)D_MODEL + EPS);
  }
  __syncthreads();
  float rinv = rinv_s;
  float4 g = ((const float4*)w)[t];
  us4 o;
  o[0] = f2bf(v.x * rinv * g.x);
  o[1] = f2bf(v.y * rinv * g.y);
  o[2] = f2bf(v.z * rinv * g.z);
  o[3] = f2bf(v.w * rinv * g.w);
  *(us4*)(xo + t*4) = o;
}

// ---------------- bf16 MFMA GEMM: C[m,n] = sum_k A[m][k]*W[n][k] ----------------
// 128x128 tile, 4 waves (2x2), each wave 64x64 = 4x4 fragments of 16x16x32.
// Fragment-contiguous LDS; global_load_lds writes base+lane*16B linearly.
// EPI: 0 = none, 2 = + resid[m*ldc+n]
template<int EPI>
__global__ __launch_bounds__(256) void gemm_bf16_kernel(
    const unsigned short* __restrict__ A,   // [M][K] bf16
    const unsigned short* __restrict__ W,   // [N][K] bf16
    float* __restrict__ C, int ldc, int K,
    const float* __restrict__ resid)
{
  __shared__ __align__(16) unsigned short Abuf[8*64*8];
  __shared__ __align__(16) unsigned short Bbuf[8*64*8];
  int tid = threadIdx.x;
  int lane = tid & 63;
  int w = tid >> 6;
  int bm = blockIdx.x * 128;
  int bn = blockIdx.y * 128;
  int wrow = (w >> 1) * 64;
  int wcol = (w & 1) * 64;

  int r15 = lane & 15, g = lane >> 4;
  const unsigned short* Ag0 = A + (size_t)(bm + 2*w*16 + r15) * K + g*8;
  const unsigned short* Ag1 = Ag0 + (size_t)16 * K;
  const unsigned short* Wg0 = W + (size_t)(bn + 2*w*16 + r15) * K + g*8;
  const unsigned short* Wg1 = Wg0 + (size_t)16 * K;
  unsigned short* Al0 = &Abuf[(2*w  )*512];
  unsigned short* Al1 = &Abuf[(2*w+1)*512];
  unsigned short* Bl0 = &Bbuf[(2*w  )*512];
  unsigned short* Bl1 = &Bbuf[(2*w+1)*512];

  f32x4 acc[4][4] = {};

  for (int k0 = 0; k0 < K; k0 += 32) {
    __syncthreads();
    __builtin_amdgcn_global_load_lds((const __attribute__((address_space(1))) void*)(Ag0 + k0),
                                     (__attribute__((address_space(3))) void*)Al0, 16, 0, 0);
    __builtin_amdgcn_global_load_lds((const __attribute__((address_space(1))) void*)(Ag1 + k0),
                                     (__attribute__((address_space(3))) void*)Al1, 16, 0, 0);
    __builtin_amdgcn_global_load_lds((const __attribute__((address_space(1))) void*)(Wg0 + k0),
                                     (__attribute__((address_space(3))) void*)Bl0, 16, 0, 0);
    __builtin_amdgcn_global_load_lds((const __attribute__((address_space(1))) void*)(Wg1 + k0),
                                     (__attribute__((address_space(3))) void*)Bl1, 16, 0, 0);
    __syncthreads();

    short8 af[4], bfr[4];
    #pragma unroll
    for (int i = 0; i < 4; ++i)
      af[i] = *(const short8*)&Abuf[((wrow >> 4) + i)*512 + lane*8];
    #pragma unroll
    for (int j = 0; j < 4; ++j)
      bfr[j] = *(const short8*)&Bbuf[((wcol >> 4) + j)*512 + lane*8];
    #pragma unroll
    for (int i = 0; i < 4; ++i)
      #pragma unroll
      for (int j = 0; j < 4; ++j)
        acc[i][j] = __builtin_amdgcn_mfma_f32_16x16x32_bf16(af[i], bfr[j], acc[i][j], 0, 0, 0);
  }

  #pragma unroll
  for (int i = 0; i < 4; ++i) {
    #pragma unroll
    for (int j = 0; j < 4; ++j) {
      #pragma unroll
      for (int r = 0; r < 4; ++r) {
        int row = bm + wrow + i*16 + (lane >> 4)*4 + r;
        int col = bn + wcol + j*16 + (lane & 15);
        float v = acc[i][j][r];
        if (EPI == 2) v += resid[(size_t)row * ldc + col];
        C[(size_t)row * ldc + col] = v;
      }
    }
  }
}

// ---------------- Generic fp32 GEMM (small ops) ----------------
// EPI: 0 = none, 1 = softplus(acc + bias[n])
#define BM 64
#define BN 64
#define BKK 16

template<int EPI>
__global__ __launch_bounds__(256) void gemm_kernel(
    const float* __restrict__ A, int lda,
    const float* __restrict__ W,
    float* __restrict__ C, int ldc,
    int M, int N, int K,
    const float* __restrict__ bias)
{
  __shared__ float As[BKK][BM + 16];
  __shared__ float Ws[BKK][BN + 16];
  int tid = threadIdx.x;
  int bm = blockIdx.x * BM;
  int bn = blockIdx.y * BN;
  int lr = tid >> 2;
  int lc = (tid & 3) << 2;
  int tr = (tid >> 4) << 2;
  int tc = (tid & 15) << 2;
  float acc[4][4] = {};
  const float* Aptr = A + (size_t)(bm + lr) * lda + lc;
  int wr = bn + lr;
  bool wok = wr < N;
  const float* Wptr = W + (size_t)wr * K + lc;

  for (int k0 = 0; k0 < K; k0 += BKK) {
    float4 av = *(const float4*)(Aptr + k0);
    float4 wv2 = wok ? *(const float4*)(Wptr + k0) : make_float4(0.f,0.f,0.f,0.f);
    __syncthreads();
    As[lc+0][lr] = av.x; As[lc+1][lr] = av.y; As[lc+2][lr] = av.z; As[lc+3][lr] = av.w;
    Ws[lc+0][lr] = wv2.x; Ws[lc+1][lr] = wv2.y; Ws[lc+2][lr] = wv2.z; Ws[lc+3][lr] = wv2.w;
    __syncthreads();
    #pragma unroll
    for (int kk = 0; kk < BKK; ++kk) {
      float a0 = As[kk][tr+0], a1 = As[kk][tr+1], a2 = As[kk][tr+2], a3 = As[kk][tr+3];
      float w0 = Ws[kk][tc+0], w1 = Ws[kk][tc+1], w2 = Ws[kk][tc+2], w3 = Ws[kk][tc+3];
      acc[0][0] = fmaf(a0,w0,acc[0][0]); acc[0][1] = fmaf(a0,w1,acc[0][1]);
      acc[0][2] = fmaf(a0,w2,acc[0][2]); acc[0][3] = fmaf(a0,w3,acc[0][3]);
      acc[1][0] = fmaf(a1,w0,acc[1][0]); acc[1][1] = fmaf(a1,w1,acc[1][1]);
      acc[1][2] = fmaf(a1,w2,acc[1][2]); acc[1][3] = fmaf(a1,w3,acc[1][3]);
      acc[2][0] = fmaf(a2,w0,acc[2][0]); acc[2][1] = fmaf(a2,w1,acc[2][1]);
      acc[2][2] = fmaf(a2,w2,acc[2][2]); acc[2][3] = fmaf(a2,w3,acc[2][3]);
      acc[3][0] = fmaf(a3,w0,acc[3][0]); acc[3][1] = fmaf(a3,w1,acc[3][1]);
      acc[3][2] = fmaf(a3,w2,acc[3][2]); acc[3][3] = fmaf(a3,w3,acc[3][3]);
    }
  }

  #pragma unroll
  for (int i = 0; i < 4; ++i) {
    int m = bm + tr + i;
    #pragma unroll
    for (int j = 0; j < 4; ++j) {
      int nn = bn + tc + j;
      if (nn >= N) continue;
      float v = acc[i][j];
      if (EPI == 1) {
        float s = v + bias[nn];
        v = fmaxf(s, 0.f) + log1pf(__expf(-fabsf(s)));
      }
      C[(size_t)m * ldc + nn] = v;
    }
  }
}

// ---------------- depthwise causal conv1d (k=4) + SiLU ----------------
__global__ __launch_bounds__(256) void conv_silu_kernel(
    const float* __restrict__ xz, const float* __restrict__ cw,
    const float* __restrict__ cb, float* __restrict__ xc)
{
  int idx = blockIdx.x * 256 + threadIdx.x;
  int d = idx & (D_INNER - 1);
  int tok = idx >> 11;
  int l = tok & (SEQ - 1);
  float w0 = cw[d*4+0], w1 = cw[d*4+1], w2 = cw[d*4+2], w3 = cw[d*4+3];
  const float* xi = xz + (size_t)tok * (2*D_INNER) + d;
  float s = cb[d];
  s += (l >= 3 ? xi[-3*(2*D_INNER)] : 0.f) * w0;
  s += (l >= 2 ? xi[-2*(2*D_INNER)] : 0.f) * w1;
  s += (l >= 1 ? xi[-1*(2*D_INNER)] : 0.f) * w2;
  s += xi[0] * w3;
  xc[idx] = s / (1.f + __expf(-s));
}

// ================= chunked selective scan =================
// h_t = dA_t h + dBu_t is affine; chunk effect is h_end = P*h_in + He with
// P_n = exp(A_n * sum(delta)) (exact log-space product). 3 passes:
// pass1: per-(b,c,d) local scan from h=0 -> (P, He). pass2: serial combine
// over 32 chunks -> Hin. pass3: re-run chunk from Hin, emit y (+D skip, z gate).
// One lane per d-channel, h[16] in registers: no shuffles, coalesced loads.
// State layout: [((b*CCH + c)*16 + n) * D_INNER + d]  (coalesced across d).

__global__ __launch_bounds__(256) void scan_pass1(
    const float* __restrict__ delta, const float* __restrict__ dbl,
    const float* __restrict__ xc, const float* __restrict__ A_log,
    float* __restrict__ P, float* __restrict__ He)
{
  int blk = blockIdx.x;                 // B*CCH*8 blocks
  int d = (blk & 7) * 256 + threadIdx.x;
  int c = (blk >> 3) & (CCH - 1);
  int b = blk >> 8;
  float Adn[16];
  #pragma unroll
  for (int n = 0; n < 16; ++n) Adn[n] = -__expf(A_log[d*16 + n]);
  float h[16] = {};
  float sdl = 0.f;
  int tok0 = b * SEQ + c * TCH;
  for (int t = 0; t < TCH; ++t) {
    size_t tok = (size_t)(tok0 + t);
    float dl = delta[tok * D_INNER + d];
    float xcv = xc[tok * D_INNER + d];
    float u = dl * xcv;
    const float4* bp = (const float4*)(dbl + tok*96 + 64);   // wave-uniform: broadcast
    float4 b0 = bp[0], b1 = bp[1], b2 = bp[2], b3 = bp[3];
    float bv[16] = {b0.x,b0.y,b0.z,b0.w, b1.x,b1.y,b1.z,b1.w,
                    b2.x,b2.y,b2.z,b2.w, b3.x,b3.y,b3.z,b3.w};
    sdl += dl;
    #pragma unroll
    for (int n = 0; n < 16; ++n)
      h[n] = fmaf(__expf(dl * Adn[n]), h[n], u * bv[n]);
  }
  size_t base = ((size_t)(b*CCH + c) * 16) * D_INNER + d;
  #pragma unroll
  for (int n = 0; n < 16; ++n) {
    P [base + (size_t)n * D_INNER] = __expf(Adn[n] * sdl);
    He[base + (size_t)n * D_INNER] = h[n];
  }
}

__global__ __launch_bounds__(256) void scan_pass2(
    const float* __restrict__ P, const float* __restrict__ He,
    float* __restrict__ Hin)
{
  int blk = blockIdx.x;                 // B*16*8 = 256 blocks
  int d = (blk & 7) * 256 + threadIdx.x;
  int n = (blk >> 3) & 15;
  int b = blk >> 7;
  float h = 0.f;
  #pragma unroll 4
  for (int c = 0; c < CCH; ++c) {
    size_t idx = ((size_t)(b*CCH + c) * 16 + n) * D_INNER + d;
    Hin[idx] = h;                       // state entering chunk c
    h = fmaf(P[idx], h, He[idx]);
  }
}

__global__ __launch_bounds__(256) void scan_pass3(
    const float* __restrict__ delta, const float* __restrict__ dbl,
    const float* __restrict__ xc, const float* __restrict__ xz,
    const float* __restrict__ A_log, const float* __restrict__ Dp,
    const float* __restrict__ Hin, unsigned short* __restrict__ y)
{
  int blk = blockIdx.x;                 // B*CCH*8 blocks
  int d = (blk & 7) * 256 + threadIdx.x;
  int c = (blk >> 3) & (CCH - 1);
  int b = blk >> 8;
  float Adn[16];
  #pragma unroll
  for (int n = 0; n < 16; ++n) Adn[n] = -__expf(A_log[d*16 + n]);
  float Dpd = Dp[d];
  float h[16];
  size_t base = ((size_t)(b*CCH + c) * 16) * D_INNER + d;
  #pragma unroll
  for (int n = 0; n < 16; ++n) h[n] = Hin[base + (size_t)n * D_INNER];
  int tok0 = b * SEQ + c * TCH;
  for (int t = 0; t < TCH; ++t) {
    size_t tok = (size_t)(tok0 + t);
    float dl = delta[tok * D_INNER + d];
    float xcv = xc[tok * D_INNER + d];
    float u = dl * xcv;
    const float4* bp = (const float4*)(dbl + tok*96 + 64);   // B then C, contiguous
    float4 b0 = bp[0], b1 = bp[1], b2 = bp[2], b3 = bp[3];
    float4 c0 = bp[4], c1 = bp[5], c2 = bp[6], c3 = bp[7];
    float bv[16] = {b0.x,b0.y,b0.z,b0.w, b1.x,b1.y,b1.z,b1.w,
                    b2.x,b2.y,b2.z,b2.w, b3.x,b3.y,b3.z,b3.w};
    float cv[16] = {c0.x,c0.y,c0.z,c0.w, c1.x,c1.y,c1.z,c1.w,
                    c2.x,c2.y,c2.z,c2.w, c3.x,c3.y,c3.z,c3.w};
    float z = xz[tok * (2*D_INNER) + D_INNER + d];
    float acc = xcv * Dpd;
    #pragma unroll
    for (int n = 0; n < 16; ++n) {
      h[n] = fmaf(__expf(dl * Adn[n]), h[n], u * bv[n]);
      acc = fmaf(h[n], cv[n], acc);
    }
    float sz = z / (1.f + __expf(-z));
    y[tok * D_INNER + d] = f2bf(acc * sz);
  }
}

// ---------------- launch ----------------
extern "C" void kernel_launch(void* const* d_in, const int* in_sizes, int n_in,
                              void* d_out, int out_size, void* d_ws, size_t ws_size,
                              hipStream_t stream) {
  const float* x         = (const float*)d_in[0];
  const float* norm_w    = (const float*)d_in[1];
  const float* in_proj_w = (const float*)d_in[2];
  const float* conv_w    = (const float*)d_in[3];
  const float* conv_b    = (const float*)d_in[4];
  const float* x_proj_w  = (const float*)d_in[5];
  const float* dt_proj_w = (const float*)d_in[6];
  const float* dt_proj_b = (const float*)d_in[7];
  const float* A_log     = (const float*)d_in[8];
  const float* Dp        = (const float*)d_in[9];
  const float* out_proj_w= (const float*)d_in[10];
  float* out = (float*)d_out;

  char* ws = (char*)d_ws;
  float*          xz     = (float*)(ws);                    //  0.. 64 MB (step2->6)
  float*          xc     = (float*)(ws + ( 64ull<<20));     // 64.. 96 MB (3->6)
  float*          dbl    = (float*)(ws + ( 96ull<<20));     // 96.. 98 MB (4->6)
  float*          delta  = (float*)(ws + ( 98ull<<20));     // 98..130 MB (5->6)
  unsigned short* xn_bf  = (unsigned short*)(ws + (130ull<<20));  // 130..138 (1->2)
  unsigned short* w_in_bf  = (unsigned short*)(ws + (138ull<<20));// 138..146 (1b->2)
  unsigned short* w_out_bf = (unsigned short*)(ws + (146ull<<20));// 146..150 (1b->7)
  unsigned short* yb_bf  = (unsigned short*)(ws + (150ull<<20));  // 150..166 (6->7)
  float*          Pst    = (float*)(ws + (130ull<<20));     // 8 MB, over dead xn_bf
  float*          Hest   = (float*)(ws + (138ull<<20));     // 8 MB, over dead w_in_bf
  float*          Hin    = (float*)(ws + (166ull<<20));     // 166..174 MB

  // 1. RMSNorm -> bf16
  rmsnorm_kernel<<<NTOK, 256, 0, stream>>>(x, norm_w, xn_bf);

  // 1b. weight conversions fp32 -> bf16
  f2bf_kernel<<<(2*D_INNER*D_MODEL)/1024, 256, 0, stream>>>(in_proj_w, w_in_bf, 2*D_INNER*D_MODEL);
  f2bf_kernel<<<(D_MODEL*D_INNER)/1024, 256, 0, stream>>>(out_proj_w, w_out_bf, D_MODEL*D_INNER);

  // 2. in_proj (bf16 MFMA)
  {
    dim3 g(NTOK/128, (2*D_INNER)/128);
    gemm_bf16_kernel<0><<<g, 256, 0, stream>>>(xn_bf, w_in_bf, xz, 2*D_INNER, D_MODEL, nullptr);
  }

  // 3. depthwise conv + SiLU
  conv_silu_kernel<<<(NTOK*D_INNER)/256, 256, 0, stream>>>(xz, conv_w, conv_b, xc);

  // 4. x_proj (fp32)
  {
    dim3 g(NTOK/BM, (96 + BN - 1)/BN);
    gemm_kernel<0><<<g, 256, 0, stream>>>(xc, D_INNER, x_proj_w, dbl, 96,
                                          NTOK, 96, D_INNER, nullptr);
  }

  // 5. dt_proj + softplus (fp32)
  {
    dim3 g(NTOK/BM, D_INNER/BN);
    gemm_kernel<1><<<g, 256, 0, stream>>>(dbl, 96, dt_proj_w, delta, D_INNER,
                                          NTOK, D_INNER, DT_RANK, dt_proj_b);
  }

  // 6. chunked selective scan -> bf16 y
  scan_pass1<<<BATCH*CCH*8, 256, 0, stream>>>(delta, dbl, xc, A_log, Pst, Hest);
  scan_pass2<<<BATCH*16*8, 256, 0, stream>>>(Pst, Hest, Hin);
  scan_pass3<<<BATCH*CCH*8, 256, 0, stream>>>(delta, dbl, xc, xz, A_log, Dp, Hin, yb_bf);

  // 7. out_proj (bf16 MFMA) + residual
  {
    dim3 g(NTOK/128, D_MODEL/128);
    gemm_bf16_kernel<2><<<g, 256, 0, stream>>>(yb_bf, w_out_bf, out, D_MODEL, D_INNER, x);
  }
}

// Round 6
// 390.044 us; speedup vs baseline: 4.3192x; 1.3218x over previous
//
#include <hip/hip_runtime.h>
#include <hip/hip_bf16.h>
#include <math.h>

#define D_MODEL 1024
#define D_STATE 16
#define D_CONV 4
#define D_INNER 2048
#define DT_RANK 64
#define BATCH 2
#define SEQ 2048
#define NTOK (BATCH*SEQ)   // 4096
#define EPS 1e-5f
#define CCH 32             // scan chunks per sequence
#define TCH (SEQ/CCH)      // 64 tokens per chunk
#define XKS 8              // x_proj split-K factor
#define XKC (D_INNER/XKS)  // 256 K per chunk

typedef __attribute__((ext_vector_type(8))) short short8;
typedef __attribute__((ext_vector_type(4))) float f32x4;
typedef __attribute__((ext_vector_type(4))) unsigned short us4;

__device__ inline unsigned short f2bf(float f) {
  union { __hip_bfloat16 h; unsigned short u; } c;
  c.h = __float2bfloat16(f);
  return c.u;
}

#define GLL(gp, lp) __builtin_amdgcn_global_load_lds( \
    (const __attribute__((address_space(1))) void*)(gp), \
    (__attribute__((address_space(3))) void*)(lp), 16, 0, 0)

// ---------------- fp32 -> bf16 bulk convert (n multiple of 4) ----------------
__global__ __launch_bounds__(256) void f2bf_kernel(const float* __restrict__ in,
                                                   unsigned short* __restrict__ out, int n) {
  int i = (blockIdx.x * 256 + threadIdx.x) * 4;
  if (i >= n) return;
  float4 v = *(const float4*)(in + i);
  us4 o;
  o[0] = f2bf(v.x); o[1] = f2bf(v.y); o[2] = f2bf(v.z); o[3] = f2bf(v.w);
  *(us4*)(out + i) = o;
}

// ---------------- RMSNorm: one block per token, bf16 output ----------------
__global__ __launch_bounds__(256) void rmsnorm_kernel(const float* __restrict__ x,
                                                      const float* __restrict__ w,
                                                      unsigned short* __restrict__ xn) {
  int tok = blockIdx.x;
  const float* xr = x + (size_t)tok * D_MODEL;
  unsigned short* xo = xn + (size_t)tok * D_MODEL;
  int t = threadIdx.x;
  float4 v = ((const float4*)xr)[t];
  float ss = v.x*v.x + v.y*v.y + v.z*v.z + v.w*v.w;
  #pragma unroll
  for (int off = 32; off > 0; off >>= 1) ss += __shfl_down(ss, off, 64);
  __shared__ float wsum[4];
  __shared__ float rinv_s;
  int lane = t & 63, wv = t >> 6;
  if (lane == 0) wsum[wv] = ss;
  __syncthreads();
  if (t == 0) {
    float tot = wsum[0] + wsum[1] + wsum[2] + wsum[3];
    rinv_s = 1.0f / sqrtf(tot / (float)D_MODEL + EPS);
  }
  __syncthreads();
  float rinv = rinv_s;
  float4 g = ((const float4*)w)[t];
  us4 o;
  o[0] = f2bf(v.x * rinv * g.x);
  o[1] = f2bf(v.y * rinv * g.y);
  o[2] = f2bf(v.z * rinv * g.z);
  o[3] = f2bf(v.w * rinv * g.w);
  *(us4*)(xo + t*4) = o;
}

// ---------------- bf16 MFMA GEMM: C[m,n] = sum_k A[m][k]*W[n][k] ----------------
// 128x128 tile, 4 waves (2x2), each wave 64x64 = 4x4 fragments of 16x16x32.
// Fragment-contiguous LDS; global_load_lds writes base+lane*16B linearly.
// EPI: 0 = none, 1 = softplus(acc + bias[n]), 2 = + resid[m*ldc+n]
template<int EPI>
__global__ __launch_bounds__(256) void gemm_bf16_kernel(
    const unsigned short* __restrict__ A,   // [M][K] bf16
    const unsigned short* __restrict__ W,   // [N][K] bf16
    float* __restrict__ C, int ldc, int K,
    const float* __restrict__ bias,
    const float* __restrict__ resid)
{
  __shared__ __align__(16) unsigned short Abuf[8*64*8];
  __shared__ __align__(16) unsigned short Bbuf[8*64*8];
  int tid = threadIdx.x;
  int lane = tid & 63;
  int w = tid >> 6;
  int bm = blockIdx.x * 128;
  int bn = blockIdx.y * 128;
  int wrow = (w >> 1) * 64;
  int wcol = (w & 1) * 64;

  int r15 = lane & 15, g = lane >> 4;
  const unsigned short* Ag0 = A + (size_t)(bm + 2*w*16 + r15) * K + g*8;
  const unsigned short* Ag1 = Ag0 + (size_t)16 * K;
  const unsigned short* Wg0 = W + (size_t)(bn + 2*w*16 + r15) * K + g*8;
  const unsigned short* Wg1 = Wg0 + (size_t)16 * K;
  unsigned short* Al0 = &Abuf[(2*w  )*512];
  unsigned short* Al1 = &Abuf[(2*w+1)*512];
  unsigned short* Bl0 = &Bbuf[(2*w  )*512];
  unsigned short* Bl1 = &Bbuf[(2*w+1)*512];

  f32x4 acc[4][4] = {};

  for (int k0 = 0; k0 < K; k0 += 32) {
    __syncthreads();
    GLL(Ag0 + k0, Al0);
    GLL(Ag1 + k0, Al1);
    GLL(Wg0 + k0, Bl0);
    GLL(Wg1 + k0, Bl1);
    __syncthreads();

    short8 af[4], bfr[4];
    #pragma unroll
    for (int i = 0; i < 4; ++i)
      af[i] = *(const short8*)&Abuf[((wrow >> 4) + i)*512 + lane*8];
    #pragma unroll
    for (int j = 0; j < 4; ++j)
      bfr[j] = *(const short8*)&Bbuf[((wcol >> 4) + j)*512 + lane*8];
    #pragma unroll
    for (int i = 0; i < 4; ++i)
      #pragma unroll
      for (int j = 0; j < 4; ++j)
        acc[i][j] = __builtin_amdgcn_mfma_f32_16x16x32_bf16(af[i], bfr[j], acc[i][j], 0, 0, 0);
  }

  #pragma unroll
  for (int i = 0; i < 4; ++i) {
    #pragma unroll
    for (int j = 0; j < 4; ++j) {
      #pragma unroll
      for (int r = 0; r < 4; ++r) {
        int row = bm + wrow + i*16 + (lane >> 4)*4 + r;
        int col = bn + wcol + j*16 + (lane & 15);
        float v = acc[i][j][r];
        if (EPI == 1) {
          float s = v + bias[col];
          v = fmaxf(s, 0.f) + log1pf(__expf(-fabsf(s)));   // stable softplus
        } else if (EPI == 2) {
          v += resid[(size_t)row * ldc + col];
        }
        C[(size_t)row * ldc + col] = v;
      }
    }
  }
}

// ---------------- x_proj bf16 MFMA, split-K: Ppart[kc] = A[.,kc*256..]W^T ----------
// Tile 128 x 96 (N=96 = 6 fragments), 4 waves stacked on M (32 rows each).
// Grid: (M/128, XKS).
__global__ __launch_bounds__(256) void xproj_bf16_kernel(
    const unsigned short* __restrict__ A,   // [NTOK][D_INNER] bf16 (xc)
    const unsigned short* __restrict__ W,   // [96][D_INNER] bf16
    float* __restrict__ Ppart)              // [XKS][NTOK][96]
{
  __shared__ __align__(16) unsigned short Abuf[8*512];   // 8 row-blocks
  __shared__ __align__(16) unsigned short Bbuf[6*512];   // 6 col-blocks
  int tid = threadIdx.x;
  int lane = tid & 63;
  int w = tid >> 6;
  int bm = blockIdx.x * 128;
  int kc = blockIdx.y;
  const int K = D_INNER;
  int r15 = lane & 15, g = lane >> 4;

  const unsigned short* Ag0 = A + (size_t)(bm + 2*w*16 + r15) * K + g*8 + kc*XKC;
  const unsigned short* Ag1 = Ag0 + (size_t)16 * K;
  const unsigned short* Wg0 = W + (size_t)(w*16 + r15) * K + g*8 + kc*XKC;       // col-block w
  const unsigned short* Wg1 = W + (size_t)((4+w)*16 + r15) * K + g*8 + kc*XKC;   // col-block 4+w (w<2)
  unsigned short* Al0 = &Abuf[(2*w  )*512];
  unsigned short* Al1 = &Abuf[(2*w+1)*512];
  unsigned short* Bl0 = &Bbuf[w*512];
  unsigned short* Bl1 = &Bbuf[(4+w)*512];

  f32x4 acc[2][6] = {};

  for (int k0 = 0; k0 < XKC; k0 += 32) {
    __syncthreads();
    GLL(Ag0 + k0, Al0);
    GLL(Ag1 + k0, Al1);
    GLL(Wg0 + k0, Bl0);
    if (w < 2) GLL(Wg1 + k0, Bl1);
    __syncthreads();

    short8 af[2], bfr[6];
    #pragma unroll
    for (int i = 0; i < 2; ++i)
      af[i] = *(const short8*)&Abuf[(2*w + i)*512 + lane*8];
    #pragma unroll
    for (int j = 0; j < 6; ++j)
      bfr[j] = *(const short8*)&Bbuf[j*512 + lane*8];
    #pragma unroll
    for (int i = 0; i < 2; ++i)
      #pragma unroll
      for (int j = 0; j < 6; ++j)
        acc[i][j] = __builtin_amdgcn_mfma_f32_16x16x32_bf16(af[i], bfr[j], acc[i][j], 0, 0, 0);
  }

  float* out = Ppart + (size_t)kc * NTOK * 96;
  #pragma unroll
  for (int i = 0; i < 2; ++i) {
    #pragma unroll
    for (int j = 0; j < 6; ++j) {
      #pragma unroll
      for (int r = 0; r < 4; ++r) {
        int row = bm + w*32 + i*16 + (lane >> 4)*4 + r;
        int col = j*16 + (lane & 15);
        out[(size_t)row * 96 + col] = acc[i][j][r];
      }
    }
  }
}

// ---------------- x_proj reduce: sum 8 partials -> dbl fp32 + dt bf16 ----------------
__global__ __launch_bounds__(256) void xproj_reduce_kernel(
    const float* __restrict__ Ppart, float* __restrict__ dbl,
    unsigned short* __restrict__ dtbf)
{
  int idx = blockIdx.x * 256 + threadIdx.x;   // over NTOK*96
  float s = 0.f;
  #pragma unroll
  for (int k = 0; k < XKS; ++k) s += Ppart[(size_t)k * NTOK * 96 + idx];
  dbl[idx] = s;
  int row = idx / 96, col = idx - row * 96;
  if (col < DT_RANK) dtbf[(size_t)row * DT_RANK + col] = f2bf(s);
}

// ---------------- depthwise causal conv1d (k=4) + SiLU; fp32 + bf16 outputs ----------
__global__ __launch_bounds__(256) void conv_silu_kernel(
    const float* __restrict__ xz, const float* __restrict__ cw,
    const float* __restrict__ cb, float* __restrict__ xc,
    unsigned short* __restrict__ xcbf)
{
  int idx = blockIdx.x * 256 + threadIdx.x;
  int d = idx & (D_INNER - 1);
  int tok = idx >> 11;
  int l = tok & (SEQ - 1);
  float w0 = cw[d*4+0], w1 = cw[d*4+1], w2 = cw[d*4+2], w3 = cw[d*4+3];
  const float* xi = xz + (size_t)tok * (2*D_INNER) + d;
  float s = cb[d];
  s += (l >= 3 ? xi[-3*(2*D_INNER)] : 0.f) * w0;
  s += (l >= 2 ? xi[-2*(2*D_INNER)] : 0.f) * w1;
  s += (l >= 1 ? xi[-1*(2*D_INNER)] : 0.f) * w2;
  s += xi[0] * w3;
  float v = s / (1.f + __expf(-s));
  xc[idx] = v;
  xcbf[idx] = f2bf(v);
}

// ================= chunked selective scan (see R3 notes) =================
__global__ __launch_bounds__(256) void scan_pass1(
    const float* __restrict__ delta, const float* __restrict__ dbl,
    const float* __restrict__ xc, const float* __restrict__ A_log,
    float* __restrict__ P, float* __restrict__ He)
{
  int blk = blockIdx.x;                 // B*CCH*8 blocks
  int d = (blk & 7) * 256 + threadIdx.x;
  int c = (blk >> 3) & (CCH - 1);
  int b = blk >> 8;
  float Adn[16];
  #pragma unroll
  for (int n = 0; n < 16; ++n) Adn[n] = -__expf(A_log[d*16 + n]);
  float h[16] = {};
  float sdl = 0.f;
  int tok0 = b * SEQ + c * TCH;
  for (int t = 0; t < TCH; ++t) {
    size_t tok = (size_t)(tok0 + t);
    float dl = delta[tok * D_INNER + d];
    float xcv = xc[tok * D_INNER + d];
    float u = dl * xcv;
    const float4* bp = (const float4*)(dbl + tok*96 + 64);
    float4 b0 = bp[0], b1 = bp[1], b2 = bp[2], b3 = bp[3];
    float bv[16] = {b0.x,b0.y,b0.z,b0.w, b1.x,b1.y,b1.z,b1.w,
                    b2.x,b2.y,b2.z,b2.w, b3.x,b3.y,b3.z,b3.w};
    sdl += dl;
    #pragma unroll
    for (int n = 0; n < 16; ++n)
      h[n] = fmaf(__expf(dl * Adn[n]), h[n], u * bv[n]);
  }
  size_t base = ((size_t)(b*CCH + c) * 16) * D_INNER + d;
  #pragma unroll
  for (int n = 0; n < 16; ++n) {
    P [base + (size_t)n * D_INNER] = __expf(Adn[n] * sdl);
    He[base + (size_t)n * D_INNER] = h[n];
  }
}

__global__ __launch_bounds__(256) void scan_pass2(
    const float* __restrict__ P, const float* __restrict__ He,
    float* __restrict__ Hin)
{
  int blk = blockIdx.x;                 // B*16*8 = 256 blocks
  int d = (blk & 7) * 256 + threadIdx.x;
  int n = (blk >> 3) & 15;
  int b = blk >> 7;
  float h = 0.f;
  #pragma unroll 4
  for (int c = 0; c < CCH; ++c) {
    size_t idx = ((size_t)(b*CCH + c) * 16 + n) * D_INNER + d;
    Hin[idx] = h;
    h = fmaf(P[idx], h, He[idx]);
  }
}

__global__ __launch_bounds__(256) void scan_pass3(
    const float* __restrict__ delta, const float* __restrict__ dbl,
    const float* __restrict__ xc, const float* __restrict__ xz,
    const float* __restrict__ A_log, const float* __restrict__ Dp,
    const float* __restrict__ Hin, unsigned short* __restrict__ y)
{
  int blk = blockIdx.x;                 // B*CCH*8 blocks
  int d = (blk & 7) * 256 + threadIdx.x;
  int c = (blk >> 3) & (CCH - 1);
  int b = blk >> 8;
  float Adn[16];
  #pragma unroll
  for (int n = 0; n < 16; ++n) Adn[n] = -__expf(A_log[d*16 + n]);
  float Dpd = Dp[d];
  float h[16];
  size_t base = ((size_t)(b*CCH + c) * 16) * D_INNER + d;
  #pragma unroll
  for (int n = 0; n < 16; ++n) h[n] = Hin[base + (size_t)n * D_INNER];
  int tok0 = b * SEQ + c * TCH;
  for (int t = 0; t < TCH; ++t) {
    size_t tok = (size_t)(tok0 + t);
    float dl = delta[tok * D_INNER + d];
    float xcv = xc[tok * D_INNER + d];
    float u = dl * xcv;
    const float4* bp = (const float4*)(dbl + tok*96 + 64);
    float4 b0 = bp[0], b1 = bp[1], b2 = bp[2], b3 = bp[3];
    float4 c0 = bp[4], c1 = bp[5], c2 = bp[6], c3 = bp[7];
    float bv[16] = {b0.x,b0.y,b0.z,b0.w, b1.x,b1.y,b1.z,b1.w,
                    b2.x,b2.y,b2.z,b2.w, b3.x,b3.y,b3.z,b3.w};
    float cv[16] = {c0.x,c0.y,c0.z,c0.w, c1.x,c1.y,c1.z,c1.w,
                    c2.x,c2.y,c2.z,c2.w, c3.x,c3.y,c3.z,c3.w};
    float z = xz[tok * (2*D_INNER) + D_INNER + d];
    float acc = xcv * Dpd;
    #pragma unroll
    for (int n = 0; n < 16; ++n) {
      h[n] = fmaf(__expf(dl * Adn[n]), h[n], u * bv[n]);
      acc = fmaf(h[n], cv[n], acc);
    }
    float sz = z / (1.f + __expf(-z));
    y[tok * D_INNER + d] = f2bf(acc * sz);
  }
}

// ---------------- launch ----------------
extern "C" void kernel_launch(void* const* d_in, const int* in_sizes, int n_in,
                              void* d_out, int out_size, void* d_ws, size_t ws_size,
                              hipStream_t stream) {
  const float* x         = (const float*)d_in[0];
  const float* norm_w    = (const float*)d_in[1];
  const float* in_proj_w = (const float*)d_in[2];
  const float* conv_w    = (const float*)d_in[3];
  const float* conv_b    = (const float*)d_in[4];
  const float* x_proj_w  = (const float*)d_in[5];
  const float* dt_proj_w = (const float*)d_in[6];
  const float* dt_proj_b = (const float*)d_in[7];
  const float* A_log     = (const float*)d_in[8];
  const float* Dp        = (const float*)d_in[9];
  const float* out_proj_w= (const float*)d_in[10];
  float* out = (float*)d_out;

  // Workspace overlay (all lifetimes sequential; total footprint 174 MB):
  char* ws = (char*)d_ws;
  float*          xz      = (float*)(ws);                          //   0.. 64 MB (2->3,6)
  float*          xc      = (float*)(ws + ( 64ull<<20));           //  64.. 96 MB (3->6)
  float*          dbl     = (float*)(ws + ( 96ull<<20));           //  96.. 98 MB (4->6)
  float*          delta   = (float*)(ws + ( 98ull<<20));           //  98..130 MB (5->6)
  unsigned short* xcbf    = (unsigned short*)(ws + ( 98ull<<20));  //  98..114 MB (3->4; dead before delta write)
  unsigned short* xn_bf   = (unsigned short*)(ws + (130ull<<20));  // 130..138 MB (1->2)
  unsigned short* w_in_bf = (unsigned short*)(ws + (138ull<<20));  // 138..146 MB (1b->2)
  float*          Ppart   = (float*)(ws + (130ull<<20));           // 130..142.6 MB (4; over dead xn/w_in)
  unsigned short* dtbf    = (unsigned short*)(ws + (144ull<<20));  // 144..144.5 MB (4->5)
  unsigned short* w_out_bf= (unsigned short*)(ws + (146ull<<20));  // 146..150 MB (1b->7)
  unsigned short* yb_bf   = (unsigned short*)(ws + (150ull<<20));  // 150..166 MB (6->7)
  float*          Pst     = (float*)(ws + (130ull<<20));           // 130..138 MB (6; over dead Ppart)
  float*          Hest    = (float*)(ws + (138ull<<20));           // 138..146 MB (6)
  float*          Hin     = (float*)(ws + (166ull<<20));           // 166..174 MB (6)
  unsigned short* w_xp_bf = (unsigned short*)(ws + (166ull<<20));  // 0.4 MB (1b->4; dead before Hin write)
  unsigned short* w_dt_bf = (unsigned short*)(ws + (167ull<<20));  // 0.25 MB (1b->5; dead before Hin write)

  // 1. RMSNorm -> bf16
  rmsnorm_kernel<<<NTOK, 256, 0, stream>>>(x, norm_w, xn_bf);

  // 1b. weight conversions fp32 -> bf16
  f2bf_kernel<<<(2*D_INNER*D_MODEL)/1024, 256, 0, stream>>>(in_proj_w, w_in_bf, 2*D_INNER*D_MODEL);
  f2bf_kernel<<<(D_MODEL*D_INNER)/1024, 256, 0, stream>>>(out_proj_w, w_out_bf, D_MODEL*D_INNER);
  f2bf_kernel<<<(96*D_INNER)/1024, 256, 0, stream>>>(x_proj_w, w_xp_bf, 96*D_INNER);
  f2bf_kernel<<<(D_INNER*DT_RANK)/1024, 256, 0, stream>>>(dt_proj_w, w_dt_bf, D_INNER*DT_RANK);

  // 2. in_proj (bf16 MFMA)
  {
    dim3 g(NTOK/128, (2*D_INNER)/128);
    gemm_bf16_kernel<0><<<g, 256, 0, stream>>>(xn_bf, w_in_bf, xz, 2*D_INNER, D_MODEL,
                                               nullptr, nullptr);
  }

  // 3. depthwise conv + SiLU (fp32 + bf16 outputs)
  conv_silu_kernel<<<(NTOK*D_INNER)/256, 256, 0, stream>>>(xz, conv_w, conv_b, xc, xcbf);

  // 4. x_proj (bf16 MFMA, split-K=8) + reduce -> dbl fp32, dt bf16
  {
    dim3 g(NTOK/128, XKS);
    xproj_bf16_kernel<<<g, 256, 0, stream>>>(xcbf, w_xp_bf, Ppart);
    xproj_reduce_kernel<<<(NTOK*96)/256, 256, 0, stream>>>(Ppart, dbl, dtbf);
  }

  // 5. dt_proj + softplus (bf16 MFMA): [4096,64] x [2048,64]^T -> delta fp32
  {
    dim3 g(NTOK/128, D_INNER/128);
    gemm_bf16_kernel<1><<<g, 256, 0, stream>>>(dtbf, w_dt_bf, delta, D_INNER, DT_RANK,
                                               dt_proj_b, nullptr);
  }

  // 6. chunked selective scan -> bf16 y
  scan_pass1<<<BATCH*CCH*8, 256, 0, stream>>>(delta, dbl, xc, A_log, Pst, Hest);
  scan_pass2<<<BATCH*16*8, 256, 0, stream>>>(Pst, Hest, Hin);
  scan_pass3<<<BATCH*CCH*8, 256, 0, stream>>>(delta, dbl, xc, xz, A_log, Dp, Hin, yb_bf);

  // 7. out_proj (bf16 MFMA) + residual
  {
    dim3 g(NTOK/128, D_MODEL/128);
    gemm_bf16_kernel<2><<<g, 256, 0, stream>>>(yb_bf, w_out_bf, out, D_MODEL, D_INNER,
                                               nullptr, x);
  }
}

// Round 7
// 385.254 us; speedup vs baseline: 4.3729x; 1.0124x over previous
//
#include <hip/hip_runtime.h>
#include <hip/hip_bf16.h>
#include <math.h>

#define D_MODEL 1024
#define D_STATE 16
#define D_CONV 4
#define D_INNER 2048
#define DT_RANK 64
#define BATCH 2
#define SEQ 2048
#define NTOK (BATCH*SEQ)   // 4096
#define EPS 1e-5f
#define CCH 32             // scan chunks per sequence
#define TCH (SEQ/CCH)      // 64 tokens per chunk
#define XKS 8              // x_proj split-K factor
#define XKC (D_INNER/XKS)  // 256 K per chunk

typedef __attribute__((ext_vector_type(8))) short short8;
typedef __attribute__((ext_vector_type(4))) float f32x4;
typedef __attribute__((ext_vector_type(4))) unsigned short us4;

__device__ inline unsigned short f2bf(float f) {
  union { __hip_bfloat16 h; unsigned short u; } c;
  c.h = __float2bfloat16(f);
  return c.u;
}
__device__ inline float bf2f(unsigned short u) {
  union { unsigned int i; float f; } c;
  c.i = ((unsigned int)u) << 16;
  return c.f;
}

#define GLL(gp, lp) __builtin_amdgcn_global_load_lds( \
    (const __attribute__((address_space(1))) void*)(gp), \
    (__attribute__((address_space(3))) void*)(lp), 16, 0, 0)

// ---------------- fused fp32 -> bf16 convert for the 4 weight tensors ----------------
// Segments sized in 1024-element blocks (all sizes divide evenly).
__global__ __launch_bounds__(256) void f2bf4_kernel(
    const float* __restrict__ i0, unsigned short* __restrict__ o0, int b0,
    const float* __restrict__ i1, unsigned short* __restrict__ o1, int b1,
    const float* __restrict__ i2, unsigned short* __restrict__ o2, int b2,
    const float* __restrict__ i3, unsigned short* __restrict__ o3)
{
  int blk = blockIdx.x;
  const float* in; unsigned short* out; int base;
  if (blk < b0)           { in = i0; out = o0; base = blk; }
  else if (blk < b0+b1)   { in = i1; out = o1; base = blk - b0; }
  else if (blk < b0+b1+b2){ in = i2; out = o2; base = blk - b0 - b1; }
  else                    { in = i3; out = o3; base = blk - b0 - b1 - b2; }
  int i = (base*256 + threadIdx.x)*4;
  float4 v = *(const float4*)(in + i);
  us4 o;
  o[0] = f2bf(v.x); o[1] = f2bf(v.y); o[2] = f2bf(v.z); o[3] = f2bf(v.w);
  *(us4*)(out + i) = o;
}

// ---------------- RMSNorm: one block per token, bf16 output ----------------
__global__ __launch_bounds__(256) void rmsnorm_kernel(const float* __restrict__ x,
                                                      const float* __restrict__ w,
                                                      unsigned short* __restrict__ xn) {
  int tok = blockIdx.x;
  const float* xr = x + (size_t)tok * D_MODEL;
  unsigned short* xo = xn + (size_t)tok * D_MODEL;
  int t = threadIdx.x;
  float4 v = ((const float4*)xr)[t];
  float ss = v.x*v.x + v.y*v.y + v.z*v.z + v.w*v.w;
  #pragma unroll
  for (int off = 32; off > 0; off >>= 1) ss += __shfl_down(ss, off, 64);
  __shared__ float wsum[4];
  __shared__ float rinv_s;
  int lane = t & 63, wv = t >> 6;
  if (lane == 0) wsum[wv] = ss;
  __syncthreads();
  if (t == 0) {
    float tot = wsum[0] + wsum[1] + wsum[2] + wsum[3];
    rinv_s = 1.0f / sqrtf(tot / (float)D_MODEL + EPS);
  }
  __syncthreads();
  float rinv = rinv_s;
  float4 g = ((const float4*)w)[t];
  us4 o;
  o[0] = f2bf(v.x * rinv * g.x);
  o[1] = f2bf(v.y * rinv * g.y);
  o[2] = f2bf(v.z * rinv * g.z);
  o[3] = f2bf(v.w * rinv * g.w);
  *(us4*)(xo + t*4) = o;
}

// ---------------- bf16 MFMA GEMM: C[m,n] = sum_k A[m][k]*W[n][k] ----------------
// 128x128 tile, 4 waves (2x2), each wave 64x64 = 4x4 fragments of 16x16x32.
// Fragment-contiguous LDS; global_load_lds writes base+lane*16B linearly.
// EPI: 0 = none, 1 = softplus(acc + bias[n]), 2 = + resid[m*ldc+n]
// OBF: 1 = write bf16 (unsigned short) output, 0 = fp32
template<int EPI, int OBF>
__global__ __launch_bounds__(256) void gemm_bf16_kernel(
    const unsigned short* __restrict__ A,   // [M][K] bf16
    const unsigned short* __restrict__ W,   // [N][K] bf16
    void* __restrict__ Cv, int ldc, int K,
    const float* __restrict__ bias,
    const float* __restrict__ resid)
{
  __shared__ __align__(16) unsigned short Abuf[8*64*8];
  __shared__ __align__(16) unsigned short Bbuf[8*64*8];
  int tid = threadIdx.x;
  int lane = tid & 63;
  int w = tid >> 6;
  int bm = blockIdx.x * 128;
  int bn = blockIdx.y * 128;
  int wrow = (w >> 1) * 64;
  int wcol = (w & 1) * 64;

  int r15 = lane & 15, g = lane >> 4;
  const unsigned short* Ag0 = A + (size_t)(bm + 2*w*16 + r15) * K + g*8;
  const unsigned short* Ag1 = Ag0 + (size_t)16 * K;
  const unsigned short* Wg0 = W + (size_t)(bn + 2*w*16 + r15) * K + g*8;
  const unsigned short* Wg1 = Wg0 + (size_t)16 * K;
  unsigned short* Al0 = &Abuf[(2*w  )*512];
  unsigned short* Al1 = &Abuf[(2*w+1)*512];
  unsigned short* Bl0 = &Bbuf[(2*w  )*512];
  unsigned short* Bl1 = &Bbuf[(2*w+1)*512];

  f32x4 acc[4][4] = {};

  for (int k0 = 0; k0 < K; k0 += 32) {
    __syncthreads();
    GLL(Ag0 + k0, Al0);
    GLL(Ag1 + k0, Al1);
    GLL(Wg0 + k0, Bl0);
    GLL(Wg1 + k0, Bl1);
    __syncthreads();

    short8 af[4], bfr[4];
    #pragma unroll
    for (int i = 0; i < 4; ++i)
      af[i] = *(const short8*)&Abuf[((wrow >> 4) + i)*512 + lane*8];
    #pragma unroll
    for (int j = 0; j < 4; ++j)
      bfr[j] = *(const short8*)&Bbuf[((wcol >> 4) + j)*512 + lane*8];
    #pragma unroll
    for (int i = 0; i < 4; ++i)
      #pragma unroll
      for (int j = 0; j < 4; ++j)
        acc[i][j] = __builtin_amdgcn_mfma_f32_16x16x32_bf16(af[i], bfr[j], acc[i][j], 0, 0, 0);
  }

  #pragma unroll
  for (int i = 0; i < 4; ++i) {
    #pragma unroll
    for (int j = 0; j < 4; ++j) {
      #pragma unroll
      for (int r = 0; r < 4; ++r) {
        int row = bm + wrow + i*16 + (lane >> 4)*4 + r;
        int col = bn + wcol + j*16 + (lane & 15);
        float v = acc[i][j][r];
        if (EPI == 1) {
          float s = v + bias[col];
          v = fmaxf(s, 0.f) + log1pf(__expf(-fabsf(s)));   // stable softplus
        } else if (EPI == 2) {
          v += resid[(size_t)row * ldc + col];
        }
        if (OBF) ((unsigned short*)Cv)[(size_t)row * ldc + col] = f2bf(v);
        else     ((float*)Cv)[(size_t)row * ldc + col] = v;
      }
    }
  }
}

// ---------------- x_proj bf16 MFMA, split-K: Ppart[kc] = A[.,kc*256..]W^T ----------
__global__ __launch_bounds__(256) void xproj_bf16_kernel(
    const unsigned short* __restrict__ A,   // [NTOK][D_INNER] bf16 (xc)
    const unsigned short* __restrict__ W,   // [96][D_INNER] bf16
    float* __restrict__ Ppart)              // [XKS][NTOK][96]
{
  __shared__ __align__(16) unsigned short Abuf[8*512];
  __shared__ __align__(16) unsigned short Bbuf[6*512];
  int tid = threadIdx.x;
  int lane = tid & 63;
  int w = tid >> 6;
  int bm = blockIdx.x * 128;
  int kc = blockIdx.y;
  const int K = D_INNER;
  int r15 = lane & 15, g = lane >> 4;

  const unsigned short* Ag0 = A + (size_t)(bm + 2*w*16 + r15) * K + g*8 + kc*XKC;
  const unsigned short* Ag1 = Ag0 + (size_t)16 * K;
  const unsigned short* Wg0 = W + (size_t)(w*16 + r15) * K + g*8 + kc*XKC;
  const unsigned short* Wg1 = W + (size_t)((4+w)*16 + r15) * K + g*8 + kc*XKC;
  unsigned short* Al0 = &Abuf[(2*w  )*512];
  unsigned short* Al1 = &Abuf[(2*w+1)*512];
  unsigned short* Bl0 = &Bbuf[w*512];
  unsigned short* Bl1 = &Bbuf[(4+w)*512];

  f32x4 acc[2][6] = {};

  for (int k0 = 0; k0 < XKC; k0 += 32) {
    __syncthreads();
    GLL(Ag0 + k0, Al0);
    GLL(Ag1 + k0, Al1);
    GLL(Wg0 + k0, Bl0);
    if (w < 2) GLL(Wg1 + k0, Bl1);
    __syncthreads();

    short8 af[2], bfr[6];
    #pragma unroll
    for (int i = 0; i < 2; ++i)
      af[i] = *(const short8*)&Abuf[(2*w + i)*512 + lane*8];
    #pragma unroll
    for (int j = 0; j < 6; ++j)
      bfr[j] = *(const short8*)&Bbuf[j*512 + lane*8];
    #pragma unroll
    for (int i = 0; i < 2; ++i)
      #pragma unroll
      for (int j = 0; j < 6; ++j)
        acc[i][j] = __builtin_amdgcn_mfma_f32_16x16x32_bf16(af[i], bfr[j], acc[i][j], 0, 0, 0);
  }

  float* out = Ppart + (size_t)kc * NTOK * 96;
  #pragma unroll
  for (int i = 0; i < 2; ++i) {
    #pragma unroll
    for (int j = 0; j < 6; ++j) {
      #pragma unroll
      for (int r = 0; r < 4; ++r) {
        int row = bm + w*32 + i*16 + (lane >> 4)*4 + r;
        int col = j*16 + (lane & 15);
        out[(size_t)row * 96 + col] = acc[i][j][r];
      }
    }
  }
}

// ---------------- x_proj reduce: sum 8 partials -> dbl fp32 + dt bf16 ----------------
__global__ __launch_bounds__(256) void xproj_reduce_kernel(
    const float* __restrict__ Ppart, float* __restrict__ dbl,
    unsigned short* __restrict__ dtbf)
{
  int idx = blockIdx.x * 256 + threadIdx.x;   // over NTOK*96
  float s = 0.f;
  #pragma unroll
  for (int k = 0; k < XKS; ++k) s += Ppart[(size_t)k * NTOK * 96 + idx];
  dbl[idx] = s;
  int row = idx / 96, col = idx - row * 96;
  if (col < DT_RANK) dtbf[(size_t)row * DT_RANK + col] = f2bf(s);
}

// ---------------- depthwise causal conv1d (k=4) + SiLU, all bf16 ----------------
// 4 d-channels per thread (us4), token rows t-3..t.
__global__ __launch_bounds__(256) void conv_silu_kernel(
    const unsigned short* __restrict__ xz, const float* __restrict__ cw,
    const float* __restrict__ cb, unsigned short* __restrict__ xcbf)
{
  int idx = blockIdx.x * 256 + threadIdx.x;   // over NTOK*D_INNER/4
  int dq = idx & (D_INNER/4 - 1);
  int tok = idx >> 9;
  int l = tok & (SEQ - 1);
  int d = dq * 4;
  const unsigned short* xi = xz + (size_t)tok * (2*D_INNER) + d;
  us4 v3 = *(const us4*)xi;                                     // tap w3 (t)
  us4 v2 = l >= 1 ? *(const us4*)(xi - 1*(2*D_INNER)) : (us4)0; // w2 (t-1)
  us4 v1 = l >= 2 ? *(const us4*)(xi - 2*(2*D_INNER)) : (us4)0; // w1 (t-2)
  us4 v0 = l >= 3 ? *(const us4*)(xi - 3*(2*D_INNER)) : (us4)0; // w0 (t-3)
  float4 cbv = *(const float4*)(cb + d);
  float cbx[4] = {cbv.x, cbv.y, cbv.z, cbv.w};
  us4 o;
  #pragma unroll
  for (int j = 0; j < 4; ++j) {
    float4 wv = *(const float4*)(cw + (d + j) * 4);
    float s = cbx[j];
    s = fmaf(bf2f(v0[j]), wv.x, s);
    s = fmaf(bf2f(v1[j]), wv.y, s);
    s = fmaf(bf2f(v2[j]), wv.z, s);
    s = fmaf(bf2f(v3[j]), wv.w, s);
    float v = s / (1.f + __expf(-s));
    o[j] = f2bf(v);
  }
  *(us4*)(xcbf + (size_t)tok * D_INNER + d) = o;
}

// ================= chunked selective scan (bf16 inputs) =================
__global__ __launch_bounds__(256) void scan_pass1(
    const unsigned short* __restrict__ delta, const float* __restrict__ dbl,
    const unsigned short* __restrict__ xc, const float* __restrict__ A_log,
    float* __restrict__ P, float* __restrict__ He)
{
  int blk = blockIdx.x;                 // B*CCH*8 blocks
  int d = (blk & 7) * 256 + threadIdx.x;
  int c = (blk >> 3) & (CCH - 1);
  int b = blk >> 8;
  float Adn[16];
  #pragma unroll
  for (int n = 0; n < 16; ++n) Adn[n] = -__expf(A_log[d*16 + n]);
  float h[16] = {};
  float sdl = 0.f;
  int tok0 = b * SEQ + c * TCH;
  for (int t = 0; t < TCH; ++t) {
    size_t tok = (size_t)(tok0 + t);
    float dl = bf2f(delta[tok * D_INNER + d]);
    float xcv = bf2f(xc[tok * D_INNER + d]);
    float u = dl * xcv;
    const float4* bp = (const float4*)(dbl + tok*96 + 64);
    float4 b0 = bp[0], b1 = bp[1], b2 = bp[2], b3 = bp[3];
    float bv[16] = {b0.x,b0.y,b0.z,b0.w, b1.x,b1.y,b1.z,b1.w,
                    b2.x,b2.y,b2.z,b2.w, b3.x,b3.y,b3.z,b3.w};
    sdl += dl;
    #pragma unroll
    for (int n = 0; n < 16; ++n)
      h[n] = fmaf(__expf(dl * Adn[n]), h[n], u * bv[n]);
  }
  size_t base = ((size_t)(b*CCH + c) * 16) * D_INNER + d;
  #pragma unroll
  for (int n = 0; n < 16; ++n) {
    P [base + (size_t)n * D_INNER] = __expf(Adn[n] * sdl);
    He[base + (size_t)n * D_INNER] = h[n];
  }
}

__global__ __launch_bounds__(256) void scan_pass2(
    const float* __restrict__ P, const float* __restrict__ He,
    float* __restrict__ Hin)
{
  int blk = blockIdx.x;                 // B*16*8 = 256 blocks
  int d = (blk & 7) * 256 + threadIdx.x;
  int n = (blk >> 3) & 15;
  int b = blk >> 7;
  float h = 0.f;
  #pragma unroll 4
  for (int c = 0; c < CCH; ++c) {
    size_t idx = ((size_t)(b*CCH + c) * 16 + n) * D_INNER + d;
    Hin[idx] = h;
    h = fmaf(P[idx], h, He[idx]);
  }
}

__global__ __launch_bounds__(256) void scan_pass3(
    const unsigned short* __restrict__ delta, const float* __restrict__ dbl,
    const unsigned short* __restrict__ xc, const unsigned short* __restrict__ xz,
    const float* __restrict__ A_log, const float* __restrict__ Dp,
    const float* __restrict__ Hin, unsigned short* __restrict__ y)
{
  int blk = blockIdx.x;                 // B*CCH*8 blocks
  int d = (blk & 7) * 256 + threadIdx.x;
  int c = (blk >> 3) & (CCH - 1);
  int b = blk >> 8;
  float Adn[16];
  #pragma unroll
  for (int n = 0; n < 16; ++n) Adn[n] = -__expf(A_log[d*16 + n]);
  float Dpd = Dp[d];
  float h[16];
  size_t base = ((size_t)(b*CCH + c) * 16) * D_INNER + d;
  #pragma unroll
  for (int n = 0; n < 16; ++n) h[n] = Hin[base + (size_t)n * D_INNER];
  int tok0 = b * SEQ + c * TCH;
  for (int t = 0; t < TCH; ++t) {
    size_t tok = (size_t)(tok0 + t);
    float dl = bf2f(delta[tok * D_INNER + d]);
    float xcv = bf2f(xc[tok * D_INNER + d]);
    float u = dl * xcv;
    const float4* bp = (const float4*)(dbl + tok*96 + 64);
    float4 b0 = bp[0], b1 = bp[1], b2 = bp[2], b3 = bp[3];
    float4 c0 = bp[4], c1 = bp[5], c2 = bp[6], c3 = bp[7];
    float bv[16] = {b0.x,b0.y,b0.z,b0.w, b1.x,b1.y,b1.z,b1.w,
                    b2.x,b2.y,b2.z,b2.w, b3.x,b3.y,b3.z,b3.w};
    float cv[16] = {c0.x,c0.y,c0.z,c0.w, c1.x,c1.y,c1.z,c1.w,
                    c2.x,c2.y,c2.z,c2.w, c3.x,c3.y,c3.z,c3.w};
    float z = bf2f(xz[tok * (2*D_INNER) + D_INNER + d]);
    float acc = xcv * Dpd;
    #pragma unroll
    for (int n = 0; n < 16; ++n) {
      h[n] = fmaf(__expf(dl * Adn[n]), h[n], u * bv[n]);
      acc = fmaf(h[n], cv[n], acc);
    }
    float sz = z / (1.f + __expf(-z));
    y[tok * D_INNER + d] = f2bf(acc * sz);
  }
}

// ---------------- launch ----------------
extern "C" void kernel_launch(void* const* d_in, const int* in_sizes, int n_in,
                              void* d_out, int out_size, void* d_ws, size_t ws_size,
                              hipStream_t stream) {
  const float* x         = (const float*)d_in[0];
  const float* norm_w    = (const float*)d_in[1];
  const float* in_proj_w = (const float*)d_in[2];
  const float* conv_w    = (const float*)d_in[3];
  const float* conv_b    = (const float*)d_in[4];
  const float* x_proj_w  = (const float*)d_in[5];
  const float* dt_proj_w = (const float*)d_in[6];
  const float* dt_proj_b = (const float*)d_in[7];
  const float* A_log     = (const float*)d_in[8];
  const float* Dp        = (const float*)d_in[9];
  const float* out_proj_w= (const float*)d_in[10];
  float* out = (float*)d_out;

  // Workspace layout — no aliasing, total ~141 MB:
  char* ws = (char*)d_ws;
  unsigned short* xz_bf   = (unsigned short*)(ws);                 //   0.. 32 MB
  unsigned short* xc_bf   = (unsigned short*)(ws + ( 32ull<<20));  //  32.. 48 MB
  float*          dbl     = (float*)(ws + ( 48ull<<20));           //  48.. 50 MB
  unsigned short* delta_bf= (unsigned short*)(ws + ( 50ull<<20));  //  50.. 66 MB
  unsigned short* xn_bf   = (unsigned short*)(ws + ( 66ull<<20));  //  66.. 74 MB
  unsigned short* w_in_bf = (unsigned short*)(ws + ( 74ull<<20));  //  74.. 82 MB
  unsigned short* w_out_bf= (unsigned short*)(ws + ( 82ull<<20));  //  82.. 86 MB
  unsigned short* w_xp_bf = (unsigned short*)(ws + ( 86ull<<20));  //  86..86.5 MB
  unsigned short* w_dt_bf = (unsigned short*)(ws + ( 87ull<<20));  //  87..87.5 MB
  unsigned short* dtbf    = (unsigned short*)(ws + ( 88ull<<20));  //  88..88.5 MB
  float*          Ppart   = (float*)(ws + ( 89ull<<20));           //  89..101.6 MB
  float*          Pst     = (float*)(ws + (102ull<<20));           // 102..110 MB
  float*          Hest    = (float*)(ws + (110ull<<20));           // 110..118 MB
  float*          Hin     = (float*)(ws + (118ull<<20));           // 118..126 MB
  unsigned short* yb_bf   = (unsigned short*)(ws + (126ull<<20));  // 126..142 MB

  // 1. RMSNorm -> bf16
  rmsnorm_kernel<<<NTOK, 256, 0, stream>>>(x, norm_w, xn_bf);

  // 1b. all weight conversions fp32 -> bf16, one launch
  f2bf4_kernel<<<4096+2048+192+128, 256, 0, stream>>>(
      in_proj_w, w_in_bf, 4096,
      out_proj_w, w_out_bf, 2048,
      x_proj_w, w_xp_bf, 192,
      dt_proj_w, w_dt_bf);

  // 2. in_proj (bf16 MFMA) -> xz bf16
  {
    dim3 g(NTOK/128, (2*D_INNER)/128);
    gemm_bf16_kernel<0,1><<<g, 256, 0, stream>>>(xn_bf, w_in_bf, xz_bf, 2*D_INNER, D_MODEL,
                                                 nullptr, nullptr);
  }

  // 3. depthwise conv + SiLU (bf16 in/out)
  conv_silu_kernel<<<(NTOK*D_INNER/4)/256, 256, 0, stream>>>(xz_bf, conv_w, conv_b, xc_bf);

  // 4. x_proj (bf16 MFMA, split-K=8) + reduce -> dbl fp32, dt bf16
  {
    dim3 g(NTOK/128, XKS);
    xproj_bf16_kernel<<<g, 256, 0, stream>>>(xc_bf, w_xp_bf, Ppart);
    xproj_reduce_kernel<<<(NTOK*96)/256, 256, 0, stream>>>(Ppart, dbl, dtbf);
  }

  // 5. dt_proj + softplus (bf16 MFMA) -> delta bf16
  {
    dim3 g(NTOK/128, D_INNER/128);
    gemm_bf16_kernel<1,1><<<g, 256, 0, stream>>>(dtbf, w_dt_bf, delta_bf, D_INNER, DT_RANK,
                                                 dt_proj_b, nullptr);
  }

  // 6. chunked selective scan -> bf16 y
  scan_pass1<<<BATCH*CCH*8, 256, 0, stream>>>(delta_bf, dbl, xc_bf, A_log, Pst, Hest);
  scan_pass2<<<BATCH*16*8, 256, 0, stream>>>(Pst, Hest, Hin);
  scan_pass3<<<BATCH*CCH*8, 256, 0, stream>>>(delta_bf, dbl, xc_bf, xz_bf, A_log, Dp, Hin, yb_bf);

  // 7. out_proj (bf16 MFMA) + residual -> fp32 out
  {
    dim3 g(NTOK/128, D_MODEL/128);
    gemm_bf16_kernel<2,0><<<g, 256, 0, stream>>>(yb_bf, w_out_bf, out, D_MODEL, D_INNER,
                                                 nullptr, x);
  }
}

// Round 8
// 350.558 us; speedup vs baseline: 4.8057x; 1.0990x over previous
//
#include <hip/hip_runtime.h>
#include <hip/hip_bf16.h>
#include <math.h>

#define D_MODEL 1024
#define D_STATE 16
#define D_CONV 4
#define D_INNER 2048
#define DT_RANK 64
#define BATCH 2
#define SEQ 2048
#define NTOK (BATCH*SEQ)   // 4096
#define EPS 1e-5f
#define CCH 32             // scan chunks per sequence
#define TCH (SEQ/CCH)      // 64 tokens per chunk
#define XKS 8              // x_proj split-K factor
#define XKC (D_INNER/XKS)  // 256 K per chunk

typedef __attribute__((ext_vector_type(8))) short short8;
typedef __attribute__((ext_vector_type(4))) float f32x4;
typedef __attribute__((ext_vector_type(4))) unsigned short us4;

__device__ inline unsigned short f2bf(float f) {
  union { __hip_bfloat16 h; unsigned short u; } c;
  c.h = __float2bfloat16(f);
  return c.u;
}
__device__ inline float bf2f(unsigned short u) {
  union { unsigned int i; float f; } c;
  c.i = ((unsigned int)u) << 16;
  return c.f;
}

#define GLL(gp, lp) __builtin_amdgcn_global_load_lds( \
    (const __attribute__((address_space(1))) void*)(gp), \
    (__attribute__((address_space(3))) void*)(lp), 16, 0, 0)

// ---------------- fused fp32 -> bf16 convert for the 4 weight tensors ----------------
__global__ __launch_bounds__(256) void f2bf4_kernel(
    const float* __restrict__ i0, unsigned short* __restrict__ o0, int b0,
    const float* __restrict__ i1, unsigned short* __restrict__ o1, int b1,
    const float* __restrict__ i2, unsigned short* __restrict__ o2, int b2,
    const float* __restrict__ i3, unsigned short* __restrict__ o3)
{
  int blk = blockIdx.x;
  const float* in; unsigned short* out; int base;
  if (blk < b0)           { in = i0; out = o0; base = blk; }
  else if (blk < b0+b1)   { in = i1; out = o1; base = blk - b0; }
  else if (blk < b0+b1+b2){ in = i2; out = o2; base = blk - b0 - b1; }
  else                    { in = i3; out = o3; base = blk - b0 - b1 - b2; }
  int i = (base*256 + threadIdx.x)*4;
  float4 v = *(const float4*)(in + i);
  us4 o;
  o[0] = f2bf(v.x); o[1] = f2bf(v.y); o[2] = f2bf(v.z); o[3] = f2bf(v.w);
  *(us4*)(out + i) = o;
}

// ---------------- RMSNorm: one block per token, bf16 output ----------------
__global__ __launch_bounds__(256) void rmsnorm_kernel(const float* __restrict__ x,
                                                      const float* __restrict__ w,
                                                      unsigned short* __restrict__ xn) {
  int tok = blockIdx.x;
  const float* xr = x + (size_t)tok * D_MODEL;
  unsigned short* xo = xn + (size_t)tok * D_MODEL;
  int t = threadIdx.x;
  float4 v = ((const float4*)xr)[t];
  float ss = v.x*v.x + v.y*v.y + v.z*v.z + v.w*v.w;
  #pragma unroll
  for (int off = 32; off > 0; off >>= 1) ss += __shfl_down(ss, off, 64);
  __shared__ float wsum[4];
  __shared__ float rinv_s;
  int lane = t & 63, wv = t >> 6;
  if (lane == 0) wsum[wv] = ss;
  __syncthreads();
  if (t == 0) {
    float tot = wsum[0] + wsum[1] + wsum[2] + wsum[3];
    rinv_s = 1.0f / sqrtf(tot / (float)D_MODEL + EPS);
  }
  __syncthreads();
  float rinv = rinv_s;
  float4 g = ((const float4*)w)[t];
  us4 o;
  o[0] = f2bf(v.x * rinv * g.x);
  o[1] = f2bf(v.y * rinv * g.y);
  o[2] = f2bf(v.z * rinv * g.z);
  o[3] = f2bf(v.w * rinv * g.w);
  *(us4*)(xo + t*4) = o;
}

// ================== 256x256 8-phase bf16 MFMA GEMM (in_proj) ==================
// C[m,n] = sum_k A[m][k]*W[n][k], bf16 out. BK=64, 512 thr = 8 waves (2M x 4N),
// per-wave 128x64 out = acc[8][4] f32x4. LDS 128KB: 2 slots x (A 32KB + B 32KB),
// fragment-contiguous (frag = 16 rows x 32 k = 1KB, lane-linear 16B).
// Schedule: phase = quadrant (ks,ih): 4 A ds_reads (+4 B at ih=0), stage quota,
// setprio(1) 16 MFMA setprio(0), s_waitcnt vmcnt(12) (counted; drain only last
// 2 tiles), raw s_barrier. Staging of tile T: ph1(T-2):A0h0+B0x2, ph2(T-2):A0h1,
// ph3(T-2):A1h0+B1x2, ph0(T-1):A1h1 -> uniform 7-phase lookahead; each region
// overwritten only after its last read (B consumed at ih=0, reused in regs).
template<int NT>   // K = NT*64
__global__ __launch_bounds__(512) void gemm256_bf16_kernel(
    const unsigned short* __restrict__ A,   // [M][K]
    const unsigned short* __restrict__ W,   // [N][K]
    unsigned short* __restrict__ C, int ldc)
{
  const int K = NT*64;
  __shared__ __align__(16) unsigned short As[2][16384];
  __shared__ __align__(16) unsigned short Bs[2][16384];
  int tid = threadIdx.x;
  int lane = tid & 63;
  int w = tid >> 6;          // 0..7
  int wm = w >> 2, wn = w & 3;
  int bm = blockIdx.x * 256;
  int bn = blockIdx.y * 256;
  int r15 = lane & 15, g8 = (lane >> 4) * 8;
  int rbh0 = (w & 3) + (w >> 2) * 8;   // this wave's ih0 staging row-block
  int rbh1 = rbh0 + 4;                 // ih1 staging row-block

  auto stageA = [&](int slot, int tile, int ks, int rb) {
    const unsigned short* src = A + (size_t)(bm + rb*16 + r15) * K + tile*64 + ks*32 + g8;
    GLL(src, &As[slot][rb*1024 + ks*512]);
  };
  auto stageB = [&](int slot, int tile, int ks, int cb) {
    const unsigned short* src = W + (size_t)(bn + cb*16 + r15) * K + tile*64 + ks*32 + g8;
    GLL(src, &Bs[slot][cb*1024 + ks*512]);
  };

  // Prologue: tile0 full (8 rounds), tile1 first 7 rounds (A1h1 staged by ph0(0)).
  stageA(0,0,0,rbh0); stageB(0,0,0,w); stageB(0,0,0,8+w);
  stageA(0,0,0,rbh1);
  stageA(0,0,1,rbh0); stageB(0,0,1,w); stageB(0,0,1,8+w);
  stageA(0,0,1,rbh1);
  stageA(1,1,0,rbh0); stageB(1,1,0,w); stageB(1,1,0,8+w);
  stageA(1,1,0,rbh1);
  stageA(1,1,1,rbh0); stageB(1,1,1,w); stageB(1,1,1,8+w);
  asm volatile("s_waitcnt vmcnt(7)" ::: "memory");   // tile0 resident
  __builtin_amdgcn_s_barrier();
  __builtin_amdgcn_sched_barrier(0);

  f32x4 acc[8][4] = {};
  short8 bfr[4];

#define PHASE_END()                                                      \
  if (drain) { asm volatile("s_waitcnt vmcnt(0)" ::: "memory"); }        \
  else       { asm volatile("s_waitcnt vmcnt(12)" ::: "memory"); }       \
  __builtin_amdgcn_s_barrier();                                          \
  __builtin_amdgcn_sched_barrier(0);

#define MFMA16(IH)                                                       \
  __builtin_amdgcn_s_setprio(1);                                         \
  _Pragma("unroll")                                                      \
  for (int ii = 0; ii < 4; ++ii) {                                       \
    _Pragma("unroll")                                                    \
    for (int j = 0; j < 4; ++j)                                          \
      acc[(IH)*4+ii][j] = __builtin_amdgcn_mfma_f32_16x16x32_bf16(       \
          af[ii], bfr[j], acc[(IH)*4+ii][j], 0, 0, 0);                   \
  }                                                                      \
  __builtin_amdgcn_s_setprio(0);

#define LOAD_A(KS, IH)                                                   \
  short8 af[4];                                                          \
  _Pragma("unroll")                                                      \
  for (int ii = 0; ii < 4; ++ii)                                         \
    af[ii] = *(const short8*)&As[s][(wm*8 + (IH)*4 + ii)*1024 + (KS)*512 + lane*8];

#define LOAD_B(KS)                                                       \
  _Pragma("unroll")                                                      \
  for (int j = 0; j < 4; ++j)                                            \
    bfr[j] = *(const short8*)&Bs[s][(wn*4 + j)*1024 + (KS)*512 + lane*8];

  for (int t = 0; t < NT; ++t) {
    int s = t & 1;
    const bool drain = (t >= NT-2);
    // ---- ph0: (ks0, ih0) ----
    {
      LOAD_A(0,0)
      LOAD_B(0)
      if (t+1 < NT) { stageA(s^1, t+1, 1, rbh1); }
      MFMA16(0)
      PHASE_END()
    }
    // ---- ph1: (ks0, ih1) ----
    {
      LOAD_A(0,1)
      if (t+2 < NT) { stageA(s, t+2, 0, rbh0); stageB(s, t+2, 0, w); stageB(s, t+2, 0, 8+w); }
      MFMA16(1)
      PHASE_END()
    }
    // ---- ph2: (ks1, ih0) ----
    {
      LOAD_A(1,0)
      LOAD_B(1)
      if (t+2 < NT) { stageA(s, t+2, 0, rbh1); }
      MFMA16(0)
      PHASE_END()
    }
    // ---- ph3: (ks1, ih1) ----
    {
      LOAD_A(1,1)
      if (t+2 < NT) { stageA(s, t+2, 1, rbh0); stageB(s, t+2, 1, w); stageB(s, t+2, 1, 8+w); }
      MFMA16(1)
      PHASE_END()
    }
  }
#undef PHASE_END
#undef MFMA16
#undef LOAD_A
#undef LOAD_B

  // Epilogue: bf16 out. C/D frag: row = +(lane>>4)*4+r, col = +(lane&15).
  #pragma unroll
  for (int ig = 0; ig < 8; ++ig) {
    #pragma unroll
    for (int j = 0; j < 4; ++j) {
      #pragma unroll
      for (int r = 0; r < 4; ++r) {
        int row = bm + wm*128 + ig*16 + (lane >> 4)*4 + r;
        int col = bn + wn*64 + j*16 + r15;
        C[(size_t)row * ldc + col] = f2bf(acc[ig][j][r]);
      }
    }
  }
}

// ---------------- 128x128 bf16 MFMA GEMM (out_proj / dt_proj) ----------------
// EPI: 0 = none, 1 = softplus(acc + bias[n]), 2 = + resid[m*ldc+n]
// OBF: 1 = bf16 out, 0 = fp32
template<int EPI, int OBF>
__global__ __launch_bounds__(256) void gemm_bf16_kernel(
    const unsigned short* __restrict__ A,   // [M][K] bf16
    const unsigned short* __restrict__ W,   // [N][K] bf16
    void* __restrict__ Cv, int ldc, int K,
    const float* __restrict__ bias,
    const float* __restrict__ resid)
{
  __shared__ __align__(16) unsigned short Abuf[8*64*8];
  __shared__ __align__(16) unsigned short Bbuf[8*64*8];
  int tid = threadIdx.x;
  int lane = tid & 63;
  int w = tid >> 6;
  int bm = blockIdx.x * 128;
  int bn = blockIdx.y * 128;
  int wrow = (w >> 1) * 64;
  int wcol = (w & 1) * 64;

  int r15 = lane & 15, g = lane >> 4;
  const unsigned short* Ag0 = A + (size_t)(bm + 2*w*16 + r15) * K + g*8;
  const unsigned short* Ag1 = Ag0 + (size_t)16 * K;
  const unsigned short* Wg0 = W + (size_t)(bn + 2*w*16 + r15) * K + g*8;
  const unsigned short* Wg1 = Wg0 + (size_t)16 * K;
  unsigned short* Al0 = &Abuf[(2*w  )*512];
  unsigned short* Al1 = &Abuf[(2*w+1)*512];
  unsigned short* Bl0 = &Bbuf[(2*w  )*512];
  unsigned short* Bl1 = &Bbuf[(2*w+1)*512];

  f32x4 acc[4][4] = {};

  for (int k0 = 0; k0 < K; k0 += 32) {
    __syncthreads();
    GLL(Ag0 + k0, Al0);
    GLL(Ag1 + k0, Al1);
    GLL(Wg0 + k0, Bl0);
    GLL(Wg1 + k0, Bl1);
    __syncthreads();

    short8 af[4], bfr[4];
    #pragma unroll
    for (int i = 0; i < 4; ++i)
      af[i] = *(const short8*)&Abuf[((wrow >> 4) + i)*512 + lane*8];
    #pragma unroll
    for (int j = 0; j < 4; ++j)
      bfr[j] = *(const short8*)&Bbuf[((wcol >> 4) + j)*512 + lane*8];
    #pragma unroll
    for (int i = 0; i < 4; ++i)
      #pragma unroll
      for (int j = 0; j < 4; ++j)
        acc[i][j] = __builtin_amdgcn_mfma_f32_16x16x32_bf16(af[i], bfr[j], acc[i][j], 0, 0, 0);
  }

  #pragma unroll
  for (int i = 0; i < 4; ++i) {
    #pragma unroll
    for (int j = 0; j < 4; ++j) {
      #pragma unroll
      for (int r = 0; r < 4; ++r) {
        int row = bm + wrow + i*16 + (lane >> 4)*4 + r;
        int col = bn + wcol + j*16 + (lane & 15);
        float v = acc[i][j][r];
        if (EPI == 1) {
          float s = v + bias[col];
          v = fmaxf(s, 0.f) + log1pf(__expf(-fabsf(s)));   // stable softplus
        } else if (EPI == 2) {
          v += resid[(size_t)row * ldc + col];
        }
        if (OBF) ((unsigned short*)Cv)[(size_t)row * ldc + col] = f2bf(v);
        else     ((float*)Cv)[(size_t)row * ldc + col] = v;
      }
    }
  }
}

// ---------------- x_proj bf16 MFMA, split-K: Ppart[kc] = A[.,kc*256..]W^T ----------
__global__ __launch_bounds__(256) void xproj_bf16_kernel(
    const unsigned short* __restrict__ A,   // [NTOK][D_INNER] bf16 (xc)
    const unsigned short* __restrict__ W,   // [96][D_INNER] bf16
    float* __restrict__ Ppart)              // [XKS][NTOK][96]
{
  __shared__ __align__(16) unsigned short Abuf[8*512];
  __shared__ __align__(16) unsigned short Bbuf[6*512];
  int tid = threadIdx.x;
  int lane = tid & 63;
  int w = tid >> 6;
  int bm = blockIdx.x * 128;
  int kc = blockIdx.y;
  const int K = D_INNER;
  int r15 = lane & 15, g = lane >> 4;

  const unsigned short* Ag0 = A + (size_t)(bm + 2*w*16 + r15) * K + g*8 + kc*XKC;
  const unsigned short* Ag1 = Ag0 + (size_t)16 * K;
  const unsigned short* Wg0 = W + (size_t)(w*16 + r15) * K + g*8 + kc*XKC;
  const unsigned short* Wg1 = W + (size_t)((4+w)*16 + r15) * K + g*8 + kc*XKC;
  unsigned short* Al0 = &Abuf[(2*w  )*512];
  unsigned short* Al1 = &Abuf[(2*w+1)*512];
  unsigned short* Bl0 = &Bbuf[w*512];
  unsigned short* Bl1 = &Bbuf[(4+w)*512];

  f32x4 acc[2][6] = {};

  for (int k0 = 0; k0 < XKC; k0 += 32) {
    __syncthreads();
    GLL(Ag0 + k0, Al0);
    GLL(Ag1 + k0, Al1);
    GLL(Wg0 + k0, Bl0);
    if (w < 2) GLL(Wg1 + k0, Bl1);
    __syncthreads();

    short8 af[2], bfr[6];
    #pragma unroll
    for (int i = 0; i < 2; ++i)
      af[i] = *(const short8*)&Abuf[(2*w + i)*512 + lane*8];
    #pragma unroll
    for (int j = 0; j < 6; ++j)
      bfr[j] = *(const short8*)&Bbuf[j*512 + lane*8];
    #pragma unroll
    for (int i = 0; i < 2; ++i)
      #pragma unroll
      for (int j = 0; j < 6; ++j)
        acc[i][j] = __builtin_amdgcn_mfma_f32_16x16x32_bf16(af[i], bfr[j], acc[i][j], 0, 0, 0);
  }

  float* out = Ppart + (size_t)kc * NTOK * 96;
  #pragma unroll
  for (int i = 0; i < 2; ++i) {
    #pragma unroll
    for (int j = 0; j < 6; ++j) {
      #pragma unroll
      for (int r = 0; r < 4; ++r) {
        int row = bm + w*32 + i*16 + (lane >> 4)*4 + r;
        int col = j*16 + (lane & 15);
        out[(size_t)row * 96 + col] = acc[i][j][r];
      }
    }
  }
}

// ---------------- x_proj reduce: sum 8 partials -> dbl fp32 + dt bf16 ----------------
__global__ __launch_bounds__(256) void xproj_reduce_kernel(
    const float* __restrict__ Ppart, float* __restrict__ dbl,
    unsigned short* __restrict__ dtbf)
{
  int idx = blockIdx.x * 256 + threadIdx.x;   // over NTOK*96
  float s = 0.f;
  #pragma unroll
  for (int k = 0; k < XKS; ++k) s += Ppart[(size_t)k * NTOK * 96 + idx];
  dbl[idx] = s;
  int row = idx / 96, col = idx - row * 96;
  if (col < DT_RANK) dtbf[(size_t)row * DT_RANK + col] = f2bf(s);
}

// ---------------- depthwise causal conv1d (k=4) + SiLU, all bf16 ----------------
__global__ __launch_bounds__(256) void conv_silu_kernel(
    const unsigned short* __restrict__ xz, const float* __restrict__ cw,
    const float* __restrict__ cb, unsigned short* __restrict__ xcbf)
{
  int idx = blockIdx.x * 256 + threadIdx.x;   // over NTOK*D_INNER/4
  int dq = idx & (D_INNER/4 - 1);
  int tok = idx >> 9;
  int l = tok & (SEQ - 1);
  int d = dq * 4;
  const unsigned short* xi = xz + (size_t)tok * (2*D_INNER) + d;
  us4 v3 = *(const us4*)xi;
  us4 v2 = l >= 1 ? *(const us4*)(xi - 1*(2*D_INNER)) : (us4)0;
  us4 v1 = l >= 2 ? *(const us4*)(xi - 2*(2*D_INNER)) : (us4)0;
  us4 v0 = l >= 3 ? *(const us4*)(xi - 3*(2*D_INNER)) : (us4)0;
  float4 cbv = *(const float4*)(cb + d);
  float cbx[4] = {cbv.x, cbv.y, cbv.z, cbv.w};
  us4 o;
  #pragma unroll
  for (int j = 0; j < 4; ++j) {
    float4 wv = *(const float4*)(cw + (d + j) * 4);
    float s = cbx[j];
    s = fmaf(bf2f(v0[j]), wv.x, s);
    s = fmaf(bf2f(v1[j]), wv.y, s);
    s = fmaf(bf2f(v2[j]), wv.z, s);
    s = fmaf(bf2f(v3[j]), wv.w, s);
    float v = s / (1.f + __expf(-s));
    o[j] = f2bf(v);
  }
  *(us4*)(xcbf + (size_t)tok * D_INNER + d) = o;
}

// ================= chunked selective scan (bf16 inputs) =================
__global__ __launch_bounds__(256) void scan_pass1(
    const unsigned short* __restrict__ delta, const float* __restrict__ dbl,
    const unsigned short* __restrict__ xc, const float* __restrict__ A_log,
    float* __restrict__ P, float* __restrict__ He)
{
  int blk = blockIdx.x;                 // B*CCH*8 blocks
  int d = (blk & 7) * 256 + threadIdx.x;
  int c = (blk >> 3) & (CCH - 1);
  int b = blk >> 8;
  float Adn[16];
  #pragma unroll
  for (int n = 0; n < 16; ++n) Adn[n] = -__expf(A_log[d*16 + n]);
  float h[16] = {};
  float sdl = 0.f;
  int tok0 = b * SEQ + c * TCH;
  for (int t = 0; t < TCH; ++t) {
    size_t tok = (size_t)(tok0 + t);
    float dl = bf2f(delta[tok * D_INNER + d]);
    float xcv = bf2f(xc[tok * D_INNER + d]);
    float u = dl * xcv;
    const float4* bp = (const float4*)(dbl + tok*96 + 64);
    float4 b0 = bp[0], b1 = bp[1], b2 = bp[2], b3 = bp[3];
    float bv[16] = {b0.x,b0.y,b0.z,b0.w, b1.x,b1.y,b1.z,b1.w,
                    b2.x,b2.y,b2.z,b2.w, b3.x,b3.y,b3.z,b3.w};
    sdl += dl;
    #pragma unroll
    for (int n = 0; n < 16; ++n)
      h[n] = fmaf(__expf(dl * Adn[n]), h[n], u * bv[n]);
  }
  size_t base = ((size_t)(b*CCH + c) * 16) * D_INNER + d;
  #pragma unroll
  for (int n = 0; n < 16; ++n) {
    P [base + (size_t)n * D_INNER] = __expf(Adn[n] * sdl);
    He[base + (size_t)n * D_INNER] = h[n];
  }
}

__global__ __launch_bounds__(256) void scan_pass2(
    const float* __restrict__ P, const float* __restrict__ He,
    float* __restrict__ Hin)
{
  int blk = blockIdx.x;                 // B*16*8 = 256 blocks
  int d = (blk & 7) * 256 + threadIdx.x;
  int n = (blk >> 3) & 15;
  int b = blk >> 7;
  float h = 0.f;
  #pragma unroll 4
  for (int c = 0; c < CCH; ++c) {
    size_t idx = ((size_t)(b*CCH + c) * 16 + n) * D_INNER + d;
    Hin[idx] = h;
    h = fmaf(P[idx], h, He[idx]);
  }
}

__global__ __launch_bounds__(256) void scan_pass3(
    const unsigned short* __restrict__ delta, const float* __restrict__ dbl,
    const unsigned short* __restrict__ xc, const unsigned short* __restrict__ xz,
    const float* __restrict__ A_log, const float* __restrict__ Dp,
    const float* __restrict__ Hin, unsigned short* __restrict__ y)
{
  int blk = blockIdx.x;                 // B*CCH*8 blocks
  int d = (blk & 7) * 256 + threadIdx.x;
  int c = (blk >> 3) & (CCH - 1);
  int b = blk >> 8;
  float Adn[16];
  #pragma unroll
  for (int n = 0; n < 16; ++n) Adn[n] = -__expf(A_log[d*16 + n]);
  float Dpd = Dp[d];
  float h[16];
  size_t base = ((size_t)(b*CCH + c) * 16) * D_INNER + d;
  #pragma unroll
  for (int n = 0; n < 16; ++n) h[n] = Hin[base + (size_t)n * D_INNER];
  int tok0 = b * SEQ + c * TCH;
  for (int t = 0; t < TCH; ++t) {
    size_t tok = (size_t)(tok0 + t);
    float dl = bf2f(delta[tok * D_INNER + d]);
    float xcv = bf2f(xc[tok * D_INNER + d]);
    float u = dl * xcv;
    const float4* bp = (const float4*)(dbl + tok*96 + 64);
    float4 b0 = bp[0], b1 = bp[1], b2 = bp[2], b3 = bp[3];
    float4 c0 = bp[4], c1 = bp[5], c2 = bp[6], c3 = bp[7];
    float bv[16] = {b0.x,b0.y,b0.z,b0.w, b1.x,b1.y,b1.z,b1.w,
                    b2.x,b2.y,b2.z,b2.w, b3.x,b3.y,b3.z,b3.w};
    float cv[16] = {c0.x,c0.y,c0.z,c0.w, c1.x,c1.y,c1.z,c1.w,
                    c2.x,c2.y,c2.z,c2.w, c3.x,c3.y,c3.z,c3.w};
    float z = bf2f(xz[tok * (2*D_INNER) + D_INNER + d]);
    float acc = xcv * Dpd;
    #pragma unroll
    for (int n = 0; n < 16; ++n) {
      h[n] = fmaf(__expf(dl * Adn[n]), h[n], u * bv[n]);
      acc = fmaf(h[n], cv[n], acc);
    }
    float sz = z / (1.f + __expf(-z));
    y[tok * D_INNER + d] = f2bf(acc * sz);
  }
}

// ---------------- launch ----------------
extern "C" void kernel_launch(void* const* d_in, const int* in_sizes, int n_in,
                              void* d_out, int out_size, void* d_ws, size_t ws_size,
                              hipStream_t stream) {
  const float* x         = (const float*)d_in[0];
  const float* norm_w    = (const float*)d_in[1];
  const float* in_proj_w = (const float*)d_in[2];
  const float* conv_w    = (const float*)d_in[3];
  const float* conv_b    = (const float*)d_in[4];
  const float* x_proj_w  = (const float*)d_in[5];
  const float* dt_proj_w = (const float*)d_in[6];
  const float* dt_proj_b = (const float*)d_in[7];
  const float* A_log     = (const float*)d_in[8];
  const float* Dp        = (const float*)d_in[9];
  const float* out_proj_w= (const float*)d_in[10];
  float* out = (float*)d_out;

  // Workspace layout — no aliasing, total ~141 MB:
  char* ws = (char*)d_ws;
  unsigned short* xz_bf   = (unsigned short*)(ws);                 //   0.. 32 MB
  unsigned short* xc_bf   = (unsigned short*)(ws + ( 32ull<<20));  //  32.. 48 MB
  float*          dbl     = (float*)(ws + ( 48ull<<20));           //  48.. 50 MB
  unsigned short* delta_bf= (unsigned short*)(ws + ( 50ull<<20));  //  50.. 66 MB
  unsigned short* xn_bf   = (unsigned short*)(ws + ( 66ull<<20));  //  66.. 74 MB
  unsigned short* w_in_bf = (unsigned short*)(ws + ( 74ull<<20));  //  74.. 82 MB
  unsigned short* w_out_bf= (unsigned short*)(ws + ( 82ull<<20));  //  82.. 86 MB
  unsigned short* w_xp_bf = (unsigned short*)(ws + ( 86ull<<20));  //  86..86.5 MB
  unsigned short* w_dt_bf = (unsigned short*)(ws + ( 87ull<<20));  //  87..87.5 MB
  unsigned short* dtbf    = (unsigned short*)(ws + ( 88ull<<20));  //  88..88.5 MB
  float*          Ppart   = (float*)(ws + ( 89ull<<20));           //  89..101.6 MB
  float*          Pst     = (float*)(ws + (102ull<<20));           // 102..110 MB
  float*          Hest    = (float*)(ws + (110ull<<20));           // 110..118 MB
  float*          Hin     = (float*)(ws + (118ull<<20));           // 118..126 MB
  unsigned short* yb_bf   = (unsigned short*)(ws + (126ull<<20));  // 126..142 MB

  // 1. RMSNorm -> bf16
  rmsnorm_kernel<<<NTOK, 256, 0, stream>>>(x, norm_w, xn_bf);

  // 1b. all weight conversions fp32 -> bf16, one launch
  f2bf4_kernel<<<4096+2048+192+128, 256, 0, stream>>>(
      in_proj_w, w_in_bf, 4096,
      out_proj_w, w_out_bf, 2048,
      x_proj_w, w_xp_bf, 192,
      dt_proj_w, w_dt_bf);

  // 2. in_proj (256x256 8-phase bf16 MFMA) -> xz bf16
  {
    dim3 g(NTOK/256, (2*D_INNER)/256);   // (16,16)
    gemm256_bf16_kernel<D_MODEL/64><<<g, 512, 0, stream>>>(xn_bf, w_in_bf, xz_bf, 2*D_INNER);
  }

  // 3. depthwise conv + SiLU (bf16 in/out)
  conv_silu_kernel<<<(NTOK*D_INNER/4)/256, 256, 0, stream>>>(xz_bf, conv_w, conv_b, xc_bf);

  // 4. x_proj (bf16 MFMA, split-K=8) + reduce -> dbl fp32, dt bf16
  {
    dim3 g(NTOK/128, XKS);
    xproj_bf16_kernel<<<g, 256, 0, stream>>>(xc_bf, w_xp_bf, Ppart);
    xproj_reduce_kernel<<<(NTOK*96)/256, 256, 0, stream>>>(Ppart, dbl, dtbf);
  }

  // 5. dt_proj + softplus (bf16 MFMA) -> delta bf16
  {
    dim3 g(NTOK/128, D_INNER/128);
    gemm_bf16_kernel<1,1><<<g, 256, 0, stream>>>(dtbf, w_dt_bf, delta_bf, D_INNER, DT_RANK,
                                                 dt_proj_b, nullptr);
  }

  // 6. chunked selective scan -> bf16 y
  scan_pass1<<<BATCH*CCH*8, 256, 0, stream>>>(delta_bf, dbl, xc_bf, A_log, Pst, Hest);
  scan_pass2<<<BATCH*16*8, 256, 0, stream>>>(Pst, Hest, Hin);
  scan_pass3<<<BATCH*CCH*8, 256, 0, stream>>>(delta_bf, dbl, xc_bf, xz_bf, A_log, Dp, Hin, yb_bf);

  // 7. out_proj (bf16 MFMA) + residual -> fp32 out
  {
    dim3 g(NTOK/128, D_MODEL/128);
    gemm_bf16_kernel<2,0><<<g, 256, 0, stream>>>(yb_bf, w_out_bf, out, D_MODEL, D_INNER,
                                                 nullptr, x);
  }
}